// Round 13
// baseline (76.114 us; speedup 1.0000x reference)
//
#include <hip/hip_runtime.h>
#include <hip/hip_bf16.h>

typedef __attribute__((ext_vector_type(8))) short short8;
typedef __attribute__((ext_vector_type(4))) float f32x4;

#define NTILE 16

static __device__ __forceinline__ unsigned pk2(float x, float y) {
  // v_cvt_pk_bf16_f32 (RNE)
  __hip_bfloat162 h = __float22bfloat162_rn(make_float2(x, y));
  unsigned u; __builtin_memcpy(&u, &h, 4); return u;
}

static __device__ __forceinline__ short8 cvt8(float4 a, float4 b) {
  union { unsigned u[4]; short8 s; } r;
  r.u[0] = pk2(a.x, a.y); r.u[1] = pk2(a.z, a.w);
  r.u[2] = pk2(b.x, b.y); r.u[3] = pk2(b.z, b.w);
  return r.s;
}

struct InstInfo { long base0; int stride; };
static __device__ __forceinline__ InstInfo decode_inst(int inst) {
  const int gi    = (inst < 32) ? 0 : ((inst < 48) ? 1 : 2);
  const int local = inst - ((gi == 0) ? 0 : ((gi == 1) ? 32 : 48));
  const int segs  = 4 >> gi;
  const int g     = 1024 << gi;
  const int offs  = gi;                // i % r = 0,1,2 for the three groups
  const int h     = local & 3;
  const int rem   = local >> 2;
  const int seg   = rem & (segs - 1);
  const int b     = rem >> (2 - gi);
  const int hh    = gi * 4 + h;
  InstInfo r;
  r.base0  = ((long)(b * 4096 + seg * g + offs) * 12 + hh) * 64;
  r.stride = (1 << gi) * 768;
  return r;
}

// ---- pass 1: K/V gather + bf16 pack (PLAIN layouts) + output hole-zeroing --
// Ks[inst][1024][64] row-major; Vts[inst][64][1024] row-major (V transposed).
__global__ __launch_bounds__(256)
void pack_kv(const float* __restrict__ Kg, const float* __restrict__ Vg,
             unsigned short* __restrict__ Ks, unsigned short* __restrict__ Vts,
             float* __restrict__ Og)
{
  __shared__ float vtmp[64][65];
  const int tid   = threadIdx.x;
  const int lid   = blockIdx.x;
  const int inst  = lid % 56;
  const int chunk = lid / 56;          // 64-token chunk (== pass-2 k-tile)
  const int gi    = (inst < 32) ? 0 : ((inst < 48) ? 1 : 2);
  InstInfo I = decode_inst(inst);

  {
    const int tok = tid >> 2, part = tid & 3;
    const long ro = I.base0 + (long)(chunk * 64 + tok) * I.stride + part * 16;
    const float4 k0 = *(const float4*)(Kg + ro);
    const float4 k1 = *(const float4*)(Kg + ro + 4);
    const float4 k2 = *(const float4*)(Kg + ro + 8);
    const float4 k3 = *(const float4*)(Kg + ro + 12);
    uint4 ka, kb;
    ka.x = pk2(k0.x,k0.y); ka.y = pk2(k0.z,k0.w); ka.z = pk2(k1.x,k1.y); ka.w = pk2(k1.z,k1.w);
    kb.x = pk2(k2.x,k2.y); kb.y = pk2(k2.z,k2.w); kb.z = pk2(k3.x,k3.y); kb.w = pk2(k3.z,k3.w);
    unsigned short* kd = Ks + ((long)inst*1024 + chunk*64 + tok)*64 + part*16;
    *(uint4*)kd = ka; *(uint4*)(kd + 8) = kb;

    const float4 w0 = *(const float4*)(Vg + ro);
    const float4 w1 = *(const float4*)(Vg + ro + 4);
    const float4 w2 = *(const float4*)(Vg + ro + 8);
    const float4 w3 = *(const float4*)(Vg + ro + 12);
    float* c = &vtmp[part*16][0] + tok;
    c[0*65]=w0.x;  c[1*65]=w0.y;  c[2*65]=w0.z;  c[3*65]=w0.w;
    c[4*65]=w1.x;  c[5*65]=w1.y;  c[6*65]=w1.z;  c[7*65]=w1.w;
    c[8*65]=w2.x;  c[9*65]=w2.y;  c[10*65]=w2.z; c[11*65]=w2.w;
    c[12*65]=w3.x; c[13*65]=w3.y; c[14*65]=w3.z; c[15*65]=w3.w;
  }
  __syncthreads();
  {
    const int d = tid >> 2, kp = tid & 3;
    float v[16];
#pragma unroll
    for (int i = 0; i < 16; ++i) v[i] = vtmp[d][kp*16 + i];
    unsigned short* vd = Vts + ((long)inst*64 + d)*1024 + chunk*64 + kp*16;
    uint4 wa, wb;
    wa.x = pk2(v[0], v[1]);  wa.y = pk2(v[2], v[3]);
    wa.z = pk2(v[4], v[5]);  wa.w = pk2(v[6], v[7]);
    wb.x = pk2(v[8], v[9]);  wb.y = pk2(v[10], v[11]);
    wb.z = pk2(v[12], v[13]); wb.w = pk2(v[14], v[15]);
    *(uint4*)vd = wa; *(uint4*)(vd + 8) = wb;
  }

  // ---- zero the dilation holes of this block's span (replaces 25MB memset) --
  const float4 z4 = make_float4(0.f, 0.f, 0.f, 0.f);
  if (gi == 1) {
    for (int i = tid; i < 64*16; i += 256) {
      const int t = i >> 4, pp = i & 15;
      float* op = Og + I.base0 + (long)(chunk*128 + 2*t + 0 - 1) * 768 + pp*4;
      *(float4*)op = z4;
    }
  } else if (gi == 2) {
    for (int i = tid; i < 192*16; i += 256) {
      const int row_i = i >> 4, pp = i & 15;
      const int t = row_i / 3, ddi = row_i - 3*t;
      const int dd = ddi + (ddi >= 2 ? 1 : 0);
      float* op = Og + I.base0 + (long)(chunk*256 + 4*t + dd - 2) * 768 + pp*4;
      *(float4*)op = z4;
    }
  }
}

// ---- pass 2: BARRIER-FREE flash attention --------------------------------
// K/V double-buffered in REGISTERS straight from L2-resident packed arrays;
// no LDS for K/V, no __syncthreads anywhere. P via wave-private swizzled LDS
// (same-wave DS ordering). 32 q-rows/wave, 4 waves/block, grid 448.
__global__ __launch_bounds__(256, 2)
void dilated_attn2(const float* __restrict__ Qg,
                   const unsigned short* __restrict__ Ks,
                   const unsigned short* __restrict__ Vts,
                   const int* __restrict__ causal_flag,
                   float* __restrict__ Og)
{
  __shared__ __align__(16) unsigned short P_lds[4][16][64];   // 8 KB

  const int tid  = threadIdx.x;
  const int wave = tid >> 6;
  const int lane = tid & 63;
  const int l15  = lane & 15;
  const int l4   = lane >> 4;
  const int sw   = l15 & 7;            // P-LDS swizzle key

  const int lid  = blockIdx.x;
  const int inst = lid % 56;           // 56%8==0 -> same inst => same XCD
  const int qt   = lid / 56;           // 8 q-blocks of 128 rows
  InstInfo I = decode_inst(inst);
  const int causal = *causal_flag;

  const float qscale = 0.125f * 1.44269504088896340736f;
  short8 b_q[2][2];
  int qrowf[2];
#pragma unroll
  for (int qf = 0; qf < 2; ++qf) {
    qrowf[qf] = qt*128 + wave*32 + qf*16 + l15;
    const float* qp = Qg + I.base0 + (long)qrowf[qf] * I.stride + l4 * 8;
#pragma unroll
    for (int ks = 0; ks < 2; ++ks) {
      float4 v0 = *(const float4*)(qp + ks*32);
      float4 v1 = *(const float4*)(qp + ks*32 + 4);
      v0.x *= qscale; v0.y *= qscale; v0.z *= qscale; v0.w *= qscale;
      v1.x *= qscale; v1.y *= qscale; v1.z *= qscale; v1.w *= qscale;
      b_q[qf][ks] = cvt8(v0, v1);
    }
  }

  short8 ones8;   // bf16 1.0 x8 (B operand for l row-sum MFMA)
  {
    union { unsigned u[4]; short8 s; } r;
    r.u[0] = r.u[1] = r.u[2] = r.u[3] = 0x3F803F80u;
    ones8 = r.s;
  }

  // lane-invariant offsets into the packed arrays
  const unsigned short* KsI  = Ks  + (long)inst * (1024*64) + l15*64 + l4*8;
  const unsigned short* VtsI = Vts + (long)inst * (64*1024) + (long)l15*1024 + l4*8;

  unsigned short* pw = &P_lds[wave][l15][0];
  int pwo[4];
#pragma unroll
  for (int n = 0; n < 4; ++n)
    pwo[n] = (((2*n + (l4 >> 1)) ^ sw) & 7)*8 + (l4 & 1)*4;
  const int pro0 = ((l4 ^ sw) & 7) * 8;
  const int pro1 = (((4 + l4) ^ sw) & 7) * 8;

  f32x4 Oacc[2][4];
  f32x4 accl[2];
#pragma unroll
  for (int qf = 0; qf < 2; ++qf) {
    accl[qf] = (f32x4){0.f,0.f,0.f,0.f};
#pragma unroll
    for (int n = 0; n < 4; ++n) Oacc[qf][n] = (f32x4){0.f,0.f,0.f,0.f};
  }

  // register K/V tile buffers (named per unroll phase; never runtime-indexed)
  short8 kA_A[4], kB_A[4], vA_A[4], vB_A[4];
  short8 kA_B[4], kB_B[4], vA_B[4], vB_B[4];

#define LOADT(SUF, KT) do {                                                    \
    const unsigned short* kb = KsI  + (long)(KT) * 4096;                       \
    const unsigned short* vb = VtsI + (long)(KT) * 64;                         \
    _Pragma("unroll")                                                          \
    for (int n = 0; n < 4; ++n) {                                              \
      kA_##SUF[n] = *(const short8*)(kb + n*1024);                             \
      kB_##SUF[n] = *(const short8*)(kb + n*1024 + 32);                        \
      vA_##SUF[n] = *(const short8*)(vb + (long)n*16384);                      \
      vB_##SUF[n] = *(const short8*)(vb + (long)n*16384 + 32);                 \
    }                                                                          \
  } while (0)

#define COMPUTE(SUF, KT) do {                                                  \
    f32x4 S0[4], S1[4];                                                        \
    __builtin_amdgcn_s_setprio(1);                                             \
    _Pragma("unroll")                                                          \
    for (int n = 0; n < 4; ++n) {                                              \
      f32x4 a0 = (f32x4){0.f,0.f,0.f,0.f};                                     \
      a0 = __builtin_amdgcn_mfma_f32_16x16x32_bf16(kA_##SUF[n], b_q[0][0], a0, 0,0,0); \
      a0 = __builtin_amdgcn_mfma_f32_16x16x32_bf16(kB_##SUF[n], b_q[0][1], a0, 0,0,0); \
      S0[n] = a0;                                                              \
      f32x4 a1 = (f32x4){0.f,0.f,0.f,0.f};                                     \
      a1 = __builtin_amdgcn_mfma_f32_16x16x32_bf16(kA_##SUF[n], b_q[1][0], a1, 0,0,0); \
      a1 = __builtin_amdgcn_mfma_f32_16x16x32_bf16(kB_##SUF[n], b_q[1][1], a1, 0,0,0); \
      S1[n] = a1;                                                              \
    }                                                                          \
    __builtin_amdgcn_s_setprio(0);                                             \
    if (causal) {                                                              \
      _Pragma("unroll")                                                        \
      for (int n = 0; n < 4; ++n)                                              \
        _Pragma("unroll")                                                      \
        for (int j = 0; j < 4; ++j) {                                          \
          int ktok = (KT)*64 + n*16 + l4*4 + j;                                \
          if (ktok > qrowf[0]) S0[n][j] = -INFINITY;                           \
          if (ktok > qrowf[1]) S1[n][j] = -INFINITY;                           \
        }                                                                      \
    }                                                                          \
    short8 ap0a, ap0b, ap1a, ap1b;                                             \
    {                                                                          \
      _Pragma("unroll")                                                        \
      for (int n = 0; n < 4; ++n) {                                            \
        unsigned u0 = pk2(__builtin_amdgcn_exp2f(S0[n][0]),                    \
                          __builtin_amdgcn_exp2f(S0[n][1]));                   \
        unsigned u1 = pk2(__builtin_amdgcn_exp2f(S0[n][2]),                    \
                          __builtin_amdgcn_exp2f(S0[n][3]));                   \
        *(uint2*)(pw + pwo[n]) = make_uint2(u0, u1);                           \
      }                                                                        \
      ap0a = *(const short8*)(pw + pro0);                                      \
      ap0b = *(const short8*)(pw + pro1);                                      \
      accl[0] = __builtin_amdgcn_mfma_f32_16x16x32_bf16(ap0a, ones8, accl[0], 0,0,0); \
      accl[0] = __builtin_amdgcn_mfma_f32_16x16x32_bf16(ap0b, ones8, accl[0], 0,0,0); \
    }                                                                          \
    {                                                                          \
      _Pragma("unroll")                                                        \
      for (int n = 0; n < 4; ++n) {                                            \
        unsigned u0 = pk2(__builtin_amdgcn_exp2f(S1[n][0]),                    \
                          __builtin_amdgcn_exp2f(S1[n][1]));                   \
        unsigned u1 = pk2(__builtin_amdgcn_exp2f(S1[n][2]),                    \
                          __builtin_amdgcn_exp2f(S1[n][3]));                   \
        *(uint2*)(pw + pwo[n]) = make_uint2(u0, u1);                           \
      }                                                                        \
      ap1a = *(const short8*)(pw + pro0);                                      \
      ap1b = *(const short8*)(pw + pro1);                                      \
      accl[1] = __builtin_amdgcn_mfma_f32_16x16x32_bf16(ap1a, ones8, accl[1], 0,0,0); \
      accl[1] = __builtin_amdgcn_mfma_f32_16x16x32_bf16(ap1b, ones8, accl[1], 0,0,0); \
    }                                                                          \
    _Pragma("unroll")                                                          \
    for (int n = 0; n < 4; ++n) {                                              \
      __builtin_amdgcn_s_setprio(1);                                           \
      Oacc[0][n] = __builtin_amdgcn_mfma_f32_16x16x32_bf16(ap0a, vA_##SUF[n], Oacc[0][n], 0,0,0); \
      Oacc[0][n] = __builtin_amdgcn_mfma_f32_16x16x32_bf16(ap0b, vB_##SUF[n], Oacc[0][n], 0,0,0); \
      Oacc[1][n] = __builtin_amdgcn_mfma_f32_16x16x32_bf16(ap1a, vA_##SUF[n], Oacc[1][n], 0,0,0); \
      Oacc[1][n] = __builtin_amdgcn_mfma_f32_16x16x32_bf16(ap1b, vB_##SUF[n], Oacc[1][n], 0,0,0); \
      __builtin_amdgcn_s_setprio(0);                                           \
    }                                                                          \
  } while (0)

  // ---- software-pipelined, barrier-free main loop (unroll by 2) ----
  LOADT(A, 0);
  for (int p = 0; p < NTILE/2; ++p) {
    const int kt = 2*p;
    LOADT(B, kt + 1);          // prefetch odd tile while computing even
    COMPUTE(A, kt);
    if (p < NTILE/2 - 1) LOADT(A, kt + 2);
    COMPUTE(B, kt + 1);
  }

  // ---- epilogue: O / l, dilated scatter ----
  float* ob = Og + I.base0;
#pragma unroll
  for (int qf = 0; qf < 2; ++qf)
#pragma unroll
    for (int j = 0; j < 4; ++j) {
      const float inv = 1.f / accl[qf][j];
      const int qrow = qt*128 + wave*32 + qf*16 + l4*4 + j;
      float* op = ob + (long)qrow * I.stride;
#pragma unroll
      for (int n = 0; n < 4; ++n)
        op[n*16 + l15] = Oacc[qf][n][j] * inv;
    }
}

// ---------------- fallback (R4 kernel) if workspace too small ---------------
#define LDP 72
__global__ __launch_bounds__(512, 4)
void dilated_attn_fb(const float* __restrict__ Qg,
                     const float* __restrict__ Kg,
                     const float* __restrict__ Vg,
                     const int* __restrict__ causal_flag,
                     float* __restrict__ Og)
{
  __shared__ __align__(16) unsigned short K_lds[2][64][LDP];
  __shared__ __align__(16) unsigned short Vt_lds[2][64][LDP];
  __shared__ __align__(16) unsigned short P_lds[8][16][LDP];

  const int tid  = threadIdx.x;
  const int wave = tid >> 6;
  const int lane = tid & 63;
  const int l15  = lane & 15;
  const int l4   = lane >> 4;
  const int qt   = blockIdx.x;
  InstInfo I = decode_inst(blockIdx.y);
  const int causal = *causal_flag;

  const float qscale = 0.125f * 1.44269504088896340736f;
  short8 b_q[2];
  {
    const int qrow = qt * 128 + wave * 16 + l15;
    const float* qp = Qg + I.base0 + (long)qrow * I.stride + l4 * 8;
#pragma unroll
    for (int ks = 0; ks < 2; ++ks) {
      float4 v0 = *(const float4*)(qp + ks * 32);
      float4 v1 = *(const float4*)(qp + ks * 32 + 4);
      v0.x *= qscale; v0.y *= qscale; v0.z *= qscale; v0.w *= qscale;
      v1.x *= qscale; v1.y *= qscale; v1.z *= qscale; v1.w *= qscale;
      b_q[ks] = cvt8(v0, v1);
    }
  }
  float m_run = -INFINITY, l_run = 0.f;
  f32x4 Oacc[4];
#pragma unroll
  for (int n = 0; n < 4; ++n) Oacc[n] = (f32x4){0.f,0.f,0.f,0.f};
  const int tt  = tid >> 3;
  const int cb8 = tid & 7;
  const float* kbase = Kg + I.base0 + cb8 * 8;
  const float* vbase = Vg + I.base0 + cb8 * 8;
#define STAGE_FB(BUF, A0, A1, W0, W1) do {                                     \
    *(short8*)&K_lds[BUF][tt][cb8 * 8] = cvt8(A0, A1);                         \
    unsigned p01 = pk2(W0.x, W0.y), p23 = pk2(W0.z, W0.w);                     \
    unsigned p45 = pk2(W1.x, W1.y), p67 = pk2(W1.z, W1.w);                     \
    const int col = (((tt >> 3) ^ cb8) << 3) | (tt & 7);                       \
    Vt_lds[BUF][cb8*8+0][col] = (unsigned short)(p01 & 0xffff);                \
    Vt_lds[BUF][cb8*8+1][col] = (unsigned short)(p01 >> 16);                   \
    Vt_lds[BUF][cb8*8+2][col] = (unsigned short)(p23 & 0xffff);                \
    Vt_lds[BUF][cb8*8+3][col] = (unsigned short)(p23 >> 16);                   \
    Vt_lds[BUF][cb8*8+4][col] = (unsigned short)(p45 & 0xffff);                \
    Vt_lds[BUF][cb8*8+5][col] = (unsigned short)(p45 >> 16);                   \
    Vt_lds[BUF][cb8*8+6][col] = (unsigned short)(p67 & 0xffff);                \
    Vt_lds[BUF][cb8*8+7][col] = (unsigned short)(p67 >> 16);                   \
  } while (0)
  {
    const long ro = (long)tt * I.stride;
    float4 k0 = *(const float4*)(kbase + ro);
    float4 k1 = *(const float4*)(kbase + ro + 4);
    float4 w0 = *(const float4*)(vbase + ro);
    float4 w1 = *(const float4*)(vbase + ro + 4);
    STAGE_FB(0, k0, k1, w0, w1);
  }
  __syncthreads();
  const int qrow_me = qt * 128 + wave * 16 + l15;
  for (int kt = 0; kt < NTILE; ++kt) {
    const int bsel = kt & 1;
    float4 nk0, nk1, nw0, nw1;
    const bool have_next = (kt + 1 < NTILE);
    if (have_next) {
      const long ro = (long)((kt + 1) * 64 + tt) * I.stride;
      nk0 = *(const float4*)(kbase + ro);
      nk1 = *(const float4*)(kbase + ro + 4);
      nw0 = *(const float4*)(vbase + ro);
      nw1 = *(const float4*)(vbase + ro + 4);
    }
    f32x4 S[4];
#pragma unroll
    for (int n = 0; n < 4; ++n) {
      short8 ak0 = *(const short8*)&K_lds[bsel][n*16 + l15][l4*8];
      short8 ak1 = *(const short8*)&K_lds[bsel][n*16 + l15][32 + l4*8];
      f32x4 acc = (f32x4){0.f,0.f,0.f,0.f};
      acc = __builtin_amdgcn_mfma_f32_16x16x32_bf16(ak0, b_q[0], acc, 0,0,0);
      acc = __builtin_amdgcn_mfma_f32_16x16x32_bf16(ak1, b_q[1], acc, 0,0,0);
      S[n] = acc;
    }
    if (causal) {
#pragma unroll
      for (int n = 0; n < 4; ++n)
#pragma unroll
        for (int j = 0; j < 4; ++j) {
          int ktok = kt*64 + n*16 + l4*4 + j;
          if (ktok > qrow_me) S[n][j] = -INFINITY;
        }
    }
    float pmax = S[0][0];
#pragma unroll
    for (int n = 0; n < 4; ++n)
#pragma unroll
      for (int j = 0; j < 4; ++j) pmax = fmaxf(pmax, S[n][j]);
    pmax = fmaxf(pmax, __shfl_xor(pmax, 16));
    pmax = fmaxf(pmax, __shfl_xor(pmax, 32));
    if (!__all(pmax - m_run <= 8.f)) {
      float mn = fmaxf(m_run, pmax);
      float corr = exp2f(m_run - mn);
      m_run = mn; l_run *= corr;
      float cq[4];
#pragma unroll
      for (int j = 0; j < 4; ++j) cq[j] = __shfl(corr, l4*4 + j, 16);
#pragma unroll
      for (int n = 0; n < 4; ++n)
#pragma unroll
        for (int j = 0; j < 4; ++j) Oacc[n][j] *= cq[j];
    }
    float psum = 0.f; unsigned up[4][2];
#pragma unroll
    for (int n = 0; n < 4; ++n)
#pragma unroll
      for (int s = 0; s < 2; ++s) {
        float p0 = exp2f(S[n][2*s]   - m_run);
        float p1 = exp2f(S[n][2*s+1] - m_run);
        psum += p0 + p1; up[n][s] = pk2(p0, p1);
      }
    l_run += psum;
#pragma unroll
    for (int n = 0; n < 4; ++n)
      *(uint2*)&P_lds[wave][l15][n*16 + l4*4] = make_uint2(up[n][0], up[n][1]);
    {
      short8 ap0 = *(const short8*)&P_lds[wave][l15][l4*8];
      short8 ap1 = *(const short8*)&P_lds[wave][l15][32 + l4*8];
#pragma unroll
      for (int n = 0; n < 4; ++n) {
        const int dsw = (2*n + (l15 >> 3)) & 7;
        short8 bv0 = *(const short8*)&Vt_lds[bsel][n*16 + l15][((l4 ^ dsw) & 7)*8];
        short8 bv1 = *(const short8*)&Vt_lds[bsel][n*16 + l15][(((4 + l4) ^ dsw) & 7)*8];
        Oacc[n] = __builtin_amdgcn_mfma_f32_16x16x32_bf16(ap0, bv0, Oacc[n], 0,0,0);
        Oacc[n] = __builtin_amdgcn_mfma_f32_16x16x32_bf16(ap1, bv1, Oacc[n], 0,0,0);
      }
    }
    if (have_next) STAGE_FB(bsel ^ 1, nk0, nk1, nw0, nw1);
    __syncthreads();
  }
  l_run += __shfl_xor(l_run, 16);
  l_run += __shfl_xor(l_run, 32);
  float lq[4];
#pragma unroll
  for (int j = 0; j < 4; ++j) lq[j] = __shfl(l_run, l4*4 + j, 16);
  float* ob = Og + I.base0;
#pragma unroll
  for (int j = 0; j < 4; ++j) {
    const float inv = 1.f / lq[j];
    const int qrow = qt*128 + wave*16 + l4*4 + j;
    float* op = ob + (long)qrow * I.stride;
#pragma unroll
    for (int n = 0; n < 4; ++n)
      op[n*16 + l15] = Oacc[n][j] * inv;
  }
}

extern "C" void kernel_launch(void* const* d_in, const int* in_sizes, int n_in,
                              void* d_out, int out_size, void* d_ws, size_t ws_size,
                              hipStream_t stream) {
  const float* Q = (const float*)d_in[0];
  const float* K = (const float*)d_in[1];
  const float* V = (const float*)d_in[2];
  const int* causal = (const int*)d_in[3];
  float* out = (float*)d_out;

  const size_t per = 56ull * 1024 * 64;               // elems per packed tensor
  const size_t need_pack = 2 * per * sizeof(unsigned short);   // 14.68 MB

  if (ws_size >= need_pack) {
    unsigned short* Ks  = (unsigned short*)d_ws;
    unsigned short* Vts = Ks + per;
    // pack_kv also zeroes the dilation holes -> no output memset needed
    pack_kv<<<896, 256, 0, stream>>>(K, V, Ks, Vts, out);
    dilated_attn2<<<448, 256, 0, stream>>>(Q, Ks, Vts, causal, out);
  } else {
    (void)hipMemsetAsync(d_out, 0, (size_t)out_size * sizeof(float), stream);
    dilated_attn_fb<<<dim3(8, 56), 512, 0, stream>>>(Q, K, V, causal, out);
  }
}

// Round 14
// 41.554 us; speedup vs baseline: 1.8317x; 1.8317x over previous
//
#include <hip/hip_runtime.h>
#include <hip/hip_bf16.h>

typedef __attribute__((ext_vector_type(8))) short short8;
typedef __attribute__((ext_vector_type(4))) float f32x4;
typedef __attribute__((ext_vector_type(16))) float f32x16;
typedef __attribute__((ext_vector_type(2))) unsigned uint2v;

#define NTILE 16

static __device__ __forceinline__ unsigned pk2(float x, float y) {
  // v_cvt_pk_bf16_f32 (RNE)
  __hip_bfloat162 h = __float22bfloat162_rn(make_float2(x, y));
  unsigned u; __builtin_memcpy(&u, &h, 4); return u;
}

static __device__ __forceinline__ short8 cvt8(float4 a, float4 b) {
  union { unsigned u[4]; short8 s; } r;
  r.u[0] = pk2(a.x, a.y); r.u[1] = pk2(a.z, a.w);
  r.u[2] = pk2(b.x, b.y); r.u[3] = pk2(b.z, b.w);
  return r.s;
}

static __device__ __forceinline__ void gll16(const void* g, void* l) {
  // global -> LDS DMA, 16B/lane; LDS dest = wave-uniform base + lane*16
  __builtin_amdgcn_global_load_lds(
      (__attribute__((address_space(1))) void*)const_cast<void*>(g),
      (__attribute__((address_space(3))) void*)(l), 16, 0, 0);
}

struct InstInfo { long base0; int stride; };
static __device__ __forceinline__ InstInfo decode_inst(int inst) {
  const int gi    = (inst < 32) ? 0 : ((inst < 48) ? 1 : 2);
  const int local = inst - ((gi == 0) ? 0 : ((gi == 1) ? 32 : 48));
  const int segs  = 4 >> gi;
  const int g     = 1024 << gi;
  const int offs  = gi;                // i % r = 0,1,2 for the three groups
  const int h     = local & 3;
  const int rem   = local >> 2;
  const int seg   = rem & (segs - 1);
  const int b     = rem >> (2 - gi);
  const int hh    = gi * 4 + h;
  InstInfo r;
  r.base0  = ((long)(b * 4096 + seg * g + offs) * 12 + hh) * 64;
  r.stride = (1 << gi) * 768;
  return r;
}

// ---- pass 1 (R11 version): K/V gather + bf16 pack with XOR-16B-block swizzle
// baked into global layout, + output hole-zeroing. ------------------------
__global__ __launch_bounds__(256)
void pack_kv(const float* __restrict__ Kg, const float* __restrict__ Vg,
             unsigned short* __restrict__ Ks, unsigned short* __restrict__ Vts,
             float* __restrict__ Og)
{
  __shared__ float vtmp[64][65];
  const int tid   = threadIdx.x;
  const int lid   = blockIdx.x;
  const int inst  = lid % 56;
  const int chunk = lid / 56;          // 64-token chunk (== pass-2 k-tile)
  const int gi    = (inst < 32) ? 0 : ((inst < 48) ? 1 : 2);
  InstInfo I = decode_inst(inst);

  {
    const int tok = tid >> 2, part = tid & 3;
    const long ro = I.base0 + (long)(chunk * 64 + tok) * I.stride + part * 16;
    const float4 k0 = *(const float4*)(Kg + ro);
    const float4 k1 = *(const float4*)(Kg + ro + 4);
    const float4 k2 = *(const float4*)(Kg + ro + 8);
    const float4 k3 = *(const float4*)(Kg + ro + 12);
    uint4 ka, kb;
    ka.x = pk2(k0.x,k0.y); ka.y = pk2(k0.z,k0.w); ka.z = pk2(k1.x,k1.y); ka.w = pk2(k1.z,k1.w);
    kb.x = pk2(k2.x,k2.y); kb.y = pk2(k2.z,k2.w); kb.z = pk2(k3.x,k3.y); kb.w = pk2(k3.z,k3.w);
    unsigned short* kd = Ks + ((long)inst*1024 + chunk*64 + tok)*64;
    const int c0 = (2*part)     ^ (tok & 7);
    const int c1 = (2*part + 1) ^ (tok & 7);
    *(uint4*)(kd + c0*8) = ka;
    *(uint4*)(kd + c1*8) = kb;

    const float4 w0 = *(const float4*)(Vg + ro);
    const float4 w1 = *(const float4*)(Vg + ro + 4);
    const float4 w2 = *(const float4*)(Vg + ro + 8);
    const float4 w3 = *(const float4*)(Vg + ro + 12);
    float* c = &vtmp[part*16][0] + tok;
    c[0*65]=w0.x;  c[1*65]=w0.y;  c[2*65]=w0.z;  c[3*65]=w0.w;
    c[4*65]=w1.x;  c[5*65]=w1.y;  c[6*65]=w1.z;  c[7*65]=w1.w;
    c[8*65]=w2.x;  c[9*65]=w2.y;  c[10*65]=w2.z; c[11*65]=w2.w;
    c[12*65]=w3.x; c[13*65]=w3.y; c[14*65]=w3.z; c[15*65]=w3.w;
  }
  __syncthreads();
  {
    const int d = tid >> 2, kp = tid & 3;
    float v[16];
#pragma unroll
    for (int i = 0; i < 16; ++i) v[i] = vtmp[d][kp*16 + i];
    unsigned short* vd = Vts + ((long)inst*64 + d)*1024 + chunk*64;
#pragma unroll
    for (int s = 0; s < 2; ++s) {
      const int pos = (kp*2 + s) ^ (d & 7);      // 16B-block swizzle baked in
      uint4 w;
      w.x = pk2(v[8*s+0], v[8*s+1]); w.y = pk2(v[8*s+2], v[8*s+3]);
      w.z = pk2(v[8*s+4], v[8*s+5]); w.w = pk2(v[8*s+6], v[8*s+7]);
      *(uint4*)(vd + pos*8) = w;
    }
  }

  // ---- zero the dilation holes of this block's span ----
  const float4 z4 = make_float4(0.f, 0.f, 0.f, 0.f);
  if (gi == 1) {
    for (int i = tid; i < 64*16; i += 256) {
      const int t = i >> 4, pp = i & 15;
      float* op = Og + I.base0 + (long)(chunk*128 + 2*t + 0 - 1) * 768 + pp*4;
      *(float4*)op = z4;
    }
  } else if (gi == 2) {
    for (int i = tid; i < 192*16; i += 256) {
      const int row_i = i >> 4, pp = i & 15;
      const int t = row_i / 3, ddi = row_i - 3*t;
      const int dd = ddi + (ddi >= 2 ? 1 : 0);
      float* op = Og + I.base0 + (long)(chunk*256 + 4*t + dd - 2) * 768 + pp*4;
      *(float4*)op = z4;
    }
  }
}

// ---- pass 2: 32x32 MFMA flash attention, P entirely in registers ---------
// S^T = K Q^T via mfma_f32_32x32x16 (C: col=q=lane&31, row=(j&3)+8*(j>>2)+4h).
// P^T re-slices into the PV B-operand with 4 permlane32_swap per 32 k.
// No P LDS, no l-MFMA (per-lane psum + 1 shfl). K/V staged via gll16 (dbuf).
__global__ __launch_bounds__(256, 2)
void dilated_attn2(const float* __restrict__ Qg,
                   const unsigned short* __restrict__ Ks,
                   const unsigned short* __restrict__ Vts,
                   const int* __restrict__ causal_flag,
                   float* __restrict__ Og)
{
  __shared__ __align__(16) unsigned short K_lds[2][64][64];   // 16 KB
  __shared__ __align__(16) unsigned short V_lds[2][64][64];   // 16 KB

  const int tid  = threadIdx.x;
  const int wave = tid >> 6;
  const int lane = tid & 63;
  const int l31  = lane & 31;
  const int h    = lane >> 5;
  const int swk  = l31 & 7;            // XOR swizzle key (row&7)

  const int lid  = blockIdx.x;
  const int inst = lid % 56;           // 56%8==0 -> same inst => same XCD
  const int qt   = lid / 56;           // 8 q-blocks of 128 rows
  InstInfo I = decode_inst(inst);
  const int causal = *causal_flag;

  const int q = qt*128 + wave*32 + l31;   // this lane's q-row (all 64 d)

  // ---- Q fragment (B operand): col=q, k=d = ds*16 + 8h + e ----
  const float qscale = 0.125f * 1.44269504088896340736f;
  short8 b_q[4];
  {
    const float* qp = Qg + I.base0 + (long)q * I.stride + h*8;
#pragma unroll
    for (int ds = 0; ds < 4; ++ds) {
      float4 v0 = *(const float4*)(qp + ds*16);
      float4 v1 = *(const float4*)(qp + ds*16 + 4);
      v0.x *= qscale; v0.y *= qscale; v0.z *= qscale; v0.w *= qscale;
      v1.x *= qscale; v1.y *= qscale; v1.z *= qscale; v1.w *= qscale;
      b_q[ds] = cvt8(v0, v1);
    }
  }

  // logical 16B-block i -> physical offset (elems), XOR baked by pack_kv
  int offs[4];
#pragma unroll
  for (int i = 0; i < 4; ++i) offs[i] = (((i*2 + h) ^ swk) & 7) * 8;

  // staging (identical to R11)
  const unsigned short* KsSt  = Ks  + (long)inst * (1024*64);
  const unsigned short* VtSt  = Vts + (long)inst * (64*1024);
  const int vrow = lane >> 3;
  const int vcol = (lane & 7) * 8;
  const long koffA = (long)(wave*8     + vrow)*64 + vcol;
  const long koffB = (long)((wave+4)*8 + vrow)*64 + vcol;
  const long voffA = (long)(wave*8     + vrow)*1024 + vcol;
  const long voffB = (long)((wave+4)*8 + vrow)*1024 + vcol;

  const unsigned short* kb0 = &K_lds[0][l31][0];
  const unsigned short* kb1 = &K_lds[1][l31][0];
  const unsigned short* vb0 = &V_lds[0][l31][0];
  const unsigned short* vb1 = &V_lds[1][l31][0];

  f32x16 O0 = {}, O1 = {};   // O^T, dblock 0/1: col=q, row d=db*32+(j&3)+8*(j>>2)+4h
  float psum = 0.f;

#define STAGE_G(BUF, KP, VP) do {                                              \
    gll16((KP) + koffA, &K_lds[BUF][wave*8][0]);                               \
    gll16((KP) + koffB, &K_lds[BUF][(wave+4)*8][0]);                           \
    gll16((VP) + voffA, &V_lds[BUF][wave*8][0]);                               \
    gll16((VP) + voffB, &V_lds[BUF][(wave+4)*8][0]);                           \
  } while (0)

#define PACK8(S, U) do {                                                       \
    _Pragma("unroll")                                                          \
    for (int g = 0; g < 4; ++g) {                                              \
      float e0 = __builtin_amdgcn_exp2f(S[4*g+0]);                             \
      float e1 = __builtin_amdgcn_exp2f(S[4*g+1]);                             \
      float e2 = __builtin_amdgcn_exp2f(S[4*g+2]);                             \
      float e3 = __builtin_amdgcn_exp2f(S[4*g+3]);                             \
      psum += (e0 + e1) + (e2 + e3);                                           \
      U[2*g]   = pk2(e0, e1);                                                  \
      U[2*g+1] = pk2(e2, e3);                                                  \
    }                                                                          \
  } while (0)

  // Build PV B-fragment for one 16-k slice from 4 packed u32 (lane half-swap).
#define MKFRAG(DST, Ua, Ub, Uc, Ud) do {                                       \
    uint2v r02 = __builtin_amdgcn_permlane32_swap((Ua), (Uc), false, false);   \
    uint2v r13 = __builtin_amdgcn_permlane32_swap((Ub), (Ud), false, false);   \
    union { unsigned w[4]; short8 s; } f_;                                     \
    f_.w[0] = r02[0]; f_.w[1] = r13[0]; f_.w[2] = r02[1]; f_.w[3] = r13[1];    \
    DST = f_.s;                                                                \
  } while (0)

#define COMPUTE(CUR, KT) do {                                                  \
    f32x16 S0 = {}, S1 = {};                                                   \
    __builtin_amdgcn_s_setprio(1);                                             \
    _Pragma("unroll")                                                          \
    for (int ds = 0; ds < 4; ++ds) {                                           \
      short8 k0 = *(const short8*)(kb##CUR + offs[ds]);                        \
      short8 k1 = *(const short8*)(kb##CUR + 2048 + offs[ds]);                 \
      S0 = __builtin_amdgcn_mfma_f32_32x32x16_bf16(k0, b_q[ds], S0, 0,0,0);    \
      S1 = __builtin_amdgcn_mfma_f32_32x32x16_bf16(k1, b_q[ds], S1, 0,0,0);    \
    }                                                                          \
    __builtin_amdgcn_s_setprio(0);                                             \
    if (causal) {                                                              \
      _Pragma("unroll")                                                        \
      for (int j = 0; j < 16; ++j) {                                           \
        int kt0 = (KT)*64 + (j&3) + 8*(j>>2) + 4*h;                            \
        if (kt0      > q) S0[j] = -INFINITY;                                   \
        if (kt0 + 32 > q) S1[j] = -INFINITY;                                   \
      }                                                                        \
    }                                                                          \
    unsigned u0[8], u1[8];                                                     \
    PACK8(S0, u0);                                                             \
    PACK8(S1, u1);                                                             \
    short8 P0, P1, P2, P3;                                                     \
    MKFRAG(P0, u0[0], u0[1], u0[2], u0[3]);                                    \
    MKFRAG(P1, u0[4], u0[5], u0[6], u0[7]);                                    \
    MKFRAG(P2, u1[0], u1[1], u1[2], u1[3]);                                    \
    MKFRAG(P3, u1[4], u1[5], u1[6], u1[7]);                                    \
    __builtin_amdgcn_s_setprio(1);                                             \
    {                                                                          \
      short8 v0 = *(const short8*)(vb##CUR + offs[0]);                         \
      short8 v1 = *(const short8*)(vb##CUR + 2048 + offs[0]);                  \
      O0 = __builtin_amdgcn_mfma_f32_32x32x16_bf16(v0, P0, O0, 0,0,0);         \
      O1 = __builtin_amdgcn_mfma_f32_32x32x16_bf16(v1, P0, O1, 0,0,0);         \
    }                                                                          \
    {                                                                          \
      short8 v0 = *(const short8*)(vb##CUR + offs[1]);                         \
      short8 v1 = *(const short8*)(vb##CUR + 2048 + offs[1]);                  \
      O0 = __builtin_amdgcn_mfma_f32_32x32x16_bf16(v0, P1, O0, 0,0,0);         \
      O1 = __builtin_amdgcn_mfma_f32_32x32x16_bf16(v1, P1, O1, 0,0,0);         \
    }                                                                          \
    {                                                                          \
      short8 v0 = *(const short8*)(vb##CUR + offs[2]);                         \
      short8 v1 = *(const short8*)(vb##CUR + 2048 + offs[2]);                  \
      O0 = __builtin_amdgcn_mfma_f32_32x32x16_bf16(v0, P2, O0, 0,0,0);         \
      O1 = __builtin_amdgcn_mfma_f32_32x32x16_bf16(v1, P2, O1, 0,0,0);         \
    }                                                                          \
    {                                                                          \
      short8 v0 = *(const short8*)(vb##CUR + offs[3]);                         \
      short8 v1 = *(const short8*)(vb##CUR + 2048 + offs[3]);                  \
      O0 = __builtin_amdgcn_mfma_f32_32x32x16_bf16(v0, P3, O0, 0,0,0);         \
      O1 = __builtin_amdgcn_mfma_f32_32x32x16_bf16(v1, P3, O1, 0,0,0);         \
    }                                                                          \
    __builtin_amdgcn_s_setprio(0);                                             \
  } while (0)

  // ---- prologue ----
  STAGE_G(0, KsSt, VtSt);
  __syncthreads();

  const unsigned short* kp1 = KsSt + 4096;
  const unsigned short* kp2 = KsSt + 8192;
  const unsigned short* vp1 = VtSt + 64;
  const unsigned short* vp2 = VtSt + 128;

  for (int p = 0; p < NTILE/2; ++p) {
    const int kt = 2*p;
    STAGE_G(1, kp1, vp1);
    COMPUTE(0, kt);
    __syncthreads();
    if (p < NTILE/2 - 1) STAGE_G(0, kp2, vp2);
    COMPUTE(1, kt + 1);
    __syncthreads();
    kp1 += 8192; kp2 += 8192; vp1 += 128; vp2 += 128;
  }

  // ---- epilogue: l = psum + partner half; normalize; dilated scatter ----
  const float l = psum + __shfl_xor(psum, 32);
  const float inv = 1.f / l;
  float* op = Og + I.base0 + (long)q * I.stride;
#pragma unroll
  for (int g = 0; g < 4; ++g) {
    const int d0 = 8*g + 4*h;
    float4 w0 = make_float4(O0[4*g]*inv, O0[4*g+1]*inv, O0[4*g+2]*inv, O0[4*g+3]*inv);
    float4 w1 = make_float4(O1[4*g]*inv, O1[4*g+1]*inv, O1[4*g+2]*inv, O1[4*g+3]*inv);
    *(float4*)(op + d0)      = w0;
    *(float4*)(op + 32 + d0) = w1;
  }
}

// ---------------- fallback (R4 kernel) if workspace too small ---------------
#define LDP 72
__global__ __launch_bounds__(512, 4)
void dilated_attn_fb(const float* __restrict__ Qg,
                     const float* __restrict__ Kg,
                     const float* __restrict__ Vg,
                     const int* __restrict__ causal_flag,
                     float* __restrict__ Og)
{
  __shared__ __align__(16) unsigned short K_lds[2][64][LDP];
  __shared__ __align__(16) unsigned short Vt_lds[2][64][LDP];
  __shared__ __align__(16) unsigned short P_lds[8][16][LDP];

  const int tid  = threadIdx.x;
  const int wave = tid >> 6;
  const int lane = tid & 63;
  const int l15  = lane & 15;
  const int l4   = lane >> 4;
  const int qt   = blockIdx.x;
  InstInfo I = decode_inst(blockIdx.y);
  const int causal = *causal_flag;

  const float qscale = 0.125f * 1.44269504088896340736f;
  short8 b_q[2];
  {
    const int qrow = qt * 128 + wave * 16 + l15;
    const float* qp = Qg + I.base0 + (long)qrow * I.stride + l4 * 8;
#pragma unroll
    for (int ks = 0; ks < 2; ++ks) {
      float4 v0 = *(const float4*)(qp + ks * 32);
      float4 v1 = *(const float4*)(qp + ks * 32 + 4);
      v0.x *= qscale; v0.y *= qscale; v0.z *= qscale; v0.w *= qscale;
      v1.x *= qscale; v1.y *= qscale; v1.z *= qscale; v1.w *= qscale;
      b_q[ks] = cvt8(v0, v1);
    }
  }
  float m_run = -INFINITY, l_run = 0.f;
  f32x4 Oacc[4];
#pragma unroll
  for (int n = 0; n < 4; ++n) Oacc[n] = (f32x4){0.f,0.f,0.f,0.f};
  const int tt  = tid >> 3;
  const int cb8 = tid & 7;
  const float* kbase = Kg + I.base0 + cb8 * 8;
  const float* vbase = Vg + I.base0 + cb8 * 8;
#define STAGE_FB(BUF, A0, A1, W0, W1) do {                                     \
    *(short8*)&K_lds[BUF][tt][cb8 * 8] = cvt8(A0, A1);                         \
    unsigned p01 = pk2(W0.x, W0.y), p23 = pk2(W0.z, W0.w);                     \
    unsigned p45 = pk2(W1.x, W1.y), p67 = pk2(W1.z, W1.w);                     \
    const int col = (((tt >> 3) ^ cb8) << 3) | (tt & 7);                       \
    Vt_lds[BUF][cb8*8+0][col] = (unsigned short)(p01 & 0xffff);                \
    Vt_lds[BUF][cb8*8+1][col] = (unsigned short)(p01 >> 16);                   \
    Vt_lds[BUF][cb8*8+2][col] = (unsigned short)(p23 & 0xffff);                \
    Vt_lds[BUF][cb8*8+3][col] = (unsigned short)(p23 >> 16);                   \
    Vt_lds[BUF][cb8*8+4][col] = (unsigned short)(p45 & 0xffff);                \
    Vt_lds[BUF][cb8*8+5][col] = (unsigned short)(p45 >> 16);                   \
    Vt_lds[BUF][cb8*8+6][col] = (unsigned short)(p67 & 0xffff);                \
    Vt_lds[BUF][cb8*8+7][col] = (unsigned short)(p67 >> 16);                   \
  } while (0)
  {
    const long ro = (long)tt * I.stride;
    float4 k0 = *(const float4*)(kbase + ro);
    float4 k1 = *(const float4*)(kbase + ro + 4);
    float4 w0 = *(const float4*)(vbase + ro);
    float4 w1 = *(const float4*)(vbase + ro + 4);
    STAGE_FB(0, k0, k1, w0, w1);
  }
  __syncthreads();
  const int qrow_me = qt * 128 + wave * 16 + l15;
  for (int kt = 0; kt < NTILE; ++kt) {
    const int bsel = kt & 1;
    float4 nk0, nk1, nw0, nw1;
    const bool have_next = (kt + 1 < NTILE);
    if (have_next) {
      const long ro = (long)((kt + 1) * 64 + tt) * I.stride;
      nk0 = *(const float4*)(kbase + ro);
      nk1 = *(const float4*)(kbase + ro + 4);
      nw0 = *(const float4*)(vbase + ro);
      nw1 = *(const float4*)(vbase + ro + 4);
    }
    f32x4 S[4];
#pragma unroll
    for (int n = 0; n < 4; ++n) {
      short8 ak0 = *(const short8*)&K_lds[bsel][n*16 + l15][l4*8];
      short8 ak1 = *(const short8*)&K_lds[bsel][n*16 + l15][32 + l4*8];
      f32x4 acc = (f32x4){0.f,0.f,0.f,0.f};
      acc = __builtin_amdgcn_mfma_f32_16x16x32_bf16(ak0, b_q[0], acc, 0,0,0);
      acc = __builtin_amdgcn_mfma_f32_16x16x32_bf16(ak1, b_q[1], acc, 0,0,0);
      S[n] = acc;
    }
    if (causal) {
#pragma unroll
      for (int n = 0; n < 4; ++n)
#pragma unroll
        for (int j = 0; j < 4; ++j) {
          int ktok = kt*64 + n*16 + l4*4 + j;
          if (ktok > qrow_me) S[n][j] = -INFINITY;
        }
    }
    float pmax = S[0][0];
#pragma unroll
    for (int n = 0; n < 4; ++n)
#pragma unroll
      for (int j = 0; j < 4; ++j) pmax = fmaxf(pmax, S[n][j]);
    pmax = fmaxf(pmax, __shfl_xor(pmax, 16));
    pmax = fmaxf(pmax, __shfl_xor(pmax, 32));
    if (!__all(pmax - m_run <= 8.f)) {
      float mn = fmaxf(m_run, pmax);
      float corr = exp2f(m_run - mn);
      m_run = mn; l_run *= corr;
      float cq[4];
#pragma unroll
      for (int j = 0; j < 4; ++j) cq[j] = __shfl(corr, l4*4 + j, 16);
#pragma unroll
      for (int n = 0; n < 4; ++n)
#pragma unroll
        for (int j = 0; j < 4; ++j) Oacc[n][j] *= cq[j];
    }
    float psum = 0.f; unsigned up[4][2];
#pragma unroll
    for (int n = 0; n < 4; ++n)
#pragma unroll
      for (int s = 0; s < 2; ++s) {
        float p0 = exp2f(S[n][2*s]   - m_run);
        float p1 = exp2f(S[n][2*s+1] - m_run);
        psum += p0 + p1; up[n][s] = pk2(p0, p1);
      }
    l_run += psum;
#pragma unroll
    for (int n = 0; n < 4; ++n)
      *(uint2*)&P_lds[wave][l15][n*16 + l4*4] = make_uint2(up[n][0], up[n][1]);
    {
      short8 ap0 = *(const short8*)&P_lds[wave][l15][l4*8];
      short8 ap1 = *(const short8*)&P_lds[wave][l15][32 + l4*8];
#pragma unroll
      for (int n = 0; n < 4; ++n) {
        const int dsw = (2*n + (l15 >> 3)) & 7;
        short8 bv0 = *(const short8*)&Vt_lds[bsel][n*16 + l15][((l4 ^ dsw) & 7)*8];
        short8 bv1 = *(const short8*)&Vt_lds[bsel][n*16 + l15][(((4 + l4) ^ dsw) & 7)*8];
        Oacc[n] = __builtin_amdgcn_mfma_f32_16x16x32_bf16(ap0, bv0, Oacc[n], 0,0,0);
        Oacc[n] = __builtin_amdgcn_mfma_f32_16x16x32_bf16(ap1, bv1, Oacc[n], 0,0,0);
      }
    }
    if (have_next) STAGE_FB(bsel ^ 1, nk0, nk1, nw0, nw1);
    __syncthreads();
  }
  l_run += __shfl_xor(l_run, 16);
  l_run += __shfl_xor(l_run, 32);
  float lq[4];
#pragma unroll
  for (int j = 0; j < 4; ++j) lq[j] = __shfl(l_run, l4*4 + j, 16);
  float* ob = Og + I.base0;
#pragma unroll
  for (int j = 0; j < 4; ++j) {
    const float inv = 1.f / lq[j];
    const int qrow = qt*128 + wave*16 + l4*4 + j;
    float* op = ob + (long)qrow * I.stride;
#pragma unroll
    for (int n = 0; n < 4; ++n)
      op[n*16 + l15] = Oacc[n][j] * inv;
  }
}

extern "C" void kernel_launch(void* const* d_in, const int* in_sizes, int n_in,
                              void* d_out, int out_size, void* d_ws, size_t ws_size,
                              hipStream_t stream) {
  const float* Q = (const float*)d_in[0];
  const float* K = (const float*)d_in[1];
  const float* V = (const float*)d_in[2];
  const int* causal = (const int*)d_in[3];
  float* out = (float*)d_out;

  const size_t per = 56ull * 1024 * 64;               // elems per packed tensor
  const size_t need_pack = 2 * per * sizeof(unsigned short);   // 14.68 MB

  if (ws_size >= need_pack) {
    unsigned short* Ks  = (unsigned short*)d_ws;
    unsigned short* Vts = Ks + per;
    // pack_kv also zeroes the dilation holes -> no output memset needed
    pack_kv<<<896, 256, 0, stream>>>(K, V, Ks, Vts, out);
    dilated_attn2<<<448, 256, 0, stream>>>(Q, Ks, Vts, causal, out);
  } else {
    (void)hipMemsetAsync(d_out, 0, (size_t)out_size * sizeof(float), stream);
    dilated_attn_fb<<<dim3(8, 56), 512, 0, stream>>>(Q, K, V, causal, out);
  }
}

// Round 15
// 40.533 us; speedup vs baseline: 1.8778x; 1.0252x over previous
//
#include <hip/hip_runtime.h>
#include <hip/hip_bf16.h>

typedef __attribute__((ext_vector_type(8))) short short8;
typedef __attribute__((ext_vector_type(4))) float f32x4;

#define NTILE 16

static __device__ __forceinline__ unsigned pk2(float x, float y) {
  // v_cvt_pk_bf16_f32 (RNE)
  __hip_bfloat162 h = __float22bfloat162_rn(make_float2(x, y));
  unsigned u; __builtin_memcpy(&u, &h, 4); return u;
}

static __device__ __forceinline__ short8 cvt8(float4 a, float4 b) {
  union { unsigned u[4]; short8 s; } r;
  r.u[0] = pk2(a.x, a.y); r.u[1] = pk2(a.z, a.w);
  r.u[2] = pk2(b.x, b.y); r.u[3] = pk2(b.z, b.w);
  return r.s;
}

static __device__ __forceinline__ void gll16(const void* g, void* l) {
  // global -> LDS DMA, 16B/lane; LDS dest = wave-uniform base + lane*16
  __builtin_amdgcn_global_load_lds(
      (__attribute__((address_space(1))) void*)const_cast<void*>(g),
      (__attribute__((address_space(3))) void*)(l), 16, 0, 0);
}

struct InstInfo { long base0; int stride; };
static __device__ __forceinline__ InstInfo decode_inst(int inst) {
  const int gi    = (inst < 32) ? 0 : ((inst < 48) ? 1 : 2);
  const int local = inst - ((gi == 0) ? 0 : ((gi == 1) ? 32 : 48));
  const int segs  = 4 >> gi;
  const int g     = 1024 << gi;
  const int offs  = gi;                // i % r = 0,1,2 for the three groups
  const int h     = local & 3;
  const int rem   = local >> 2;
  const int seg   = rem & (segs - 1);
  const int b     = rem >> (2 - gi);
  const int hh    = gi * 4 + h;
  InstInfo r;
  r.base0  = ((long)(b * 4096 + seg * g + offs) * 12 + hh) * 64;
  r.stride = (1 << gi) * 768;
  return r;
}

// ---- pass 1: K/V gather + bf16 pack (XOR-16B-block swizzle baked) + holes --
__global__ __launch_bounds__(256)
void pack_kv(const float* __restrict__ Kg, const float* __restrict__ Vg,
             unsigned short* __restrict__ Ks, unsigned short* __restrict__ Vts,
             float* __restrict__ Og)
{
  __shared__ float vtmp[64][65];
  const int tid   = threadIdx.x;
  const int lid   = blockIdx.x;
  const int inst  = lid % 56;
  const int chunk = lid / 56;          // 64-token chunk (== pass-2 k-tile)
  const int gi    = (inst < 32) ? 0 : ((inst < 48) ? 1 : 2);
  InstInfo I = decode_inst(inst);

  {
    const int tok = tid >> 2, part = tid & 3;
    const long ro = I.base0 + (long)(chunk * 64 + tok) * I.stride + part * 16;
    const float4 k0 = *(const float4*)(Kg + ro);
    const float4 k1 = *(const float4*)(Kg + ro + 4);
    const float4 k2 = *(const float4*)(Kg + ro + 8);
    const float4 k3 = *(const float4*)(Kg + ro + 12);
    uint4 ka, kb;
    ka.x = pk2(k0.x,k0.y); ka.y = pk2(k0.z,k0.w); ka.z = pk2(k1.x,k1.y); ka.w = pk2(k1.z,k1.w);
    kb.x = pk2(k2.x,k2.y); kb.y = pk2(k2.z,k2.w); kb.z = pk2(k3.x,k3.y); kb.w = pk2(k3.z,k3.w);
    // K: row tok of 64 elems = 8 x 16B blocks; block c stored at c ^ (tok&7)
    unsigned short* kd = Ks + ((long)inst*1024 + chunk*64 + tok)*64;
    const int c0 = (2*part)     ^ (tok & 7);
    const int c1 = (2*part + 1) ^ (tok & 7);
    *(uint4*)(kd + c0*8) = ka;
    *(uint4*)(kd + c1*8) = kb;

    const float4 w0 = *(const float4*)(Vg + ro);
    const float4 w1 = *(const float4*)(Vg + ro + 4);
    const float4 w2 = *(const float4*)(Vg + ro + 8);
    const float4 w3 = *(const float4*)(Vg + ro + 12);
    float* c = &vtmp[part*16][0] + tok;
    c[0*65]=w0.x;  c[1*65]=w0.y;  c[2*65]=w0.z;  c[3*65]=w0.w;
    c[4*65]=w1.x;  c[5*65]=w1.y;  c[6*65]=w1.z;  c[7*65]=w1.w;
    c[8*65]=w2.x;  c[9*65]=w2.y;  c[10*65]=w2.z; c[11*65]=w2.w;
    c[12*65]=w3.x; c[13*65]=w3.y; c[14*65]=w3.z; c[15*65]=w3.w;
  }
  __syncthreads();
  {
    const int d = tid >> 2, kp = tid & 3;
    float v[16];
#pragma unroll
    for (int i = 0; i < 16; ++i) v[i] = vtmp[d][kp*16 + i];
    unsigned short* vd = Vts + ((long)inst*64 + d)*1024 + chunk*64;
#pragma unroll
    for (int s = 0; s < 2; ++s) {
      const int pos = (kp*2 + s) ^ (d & 7);      // 16B-block swizzle baked in
      uint4 w;
      w.x = pk2(v[8*s+0], v[8*s+1]); w.y = pk2(v[8*s+2], v[8*s+3]);
      w.z = pk2(v[8*s+4], v[8*s+5]); w.w = pk2(v[8*s+6], v[8*s+7]);
      *(uint4*)(vd + pos*8) = w;
    }
  }

  // ---- zero the dilation holes of this block's span ----
  const float4 z4 = make_float4(0.f, 0.f, 0.f, 0.f);
  if (gi == 1) {
    for (int i = tid; i < 64*16; i += 256) {
      const int t = i >> 4, pp = i & 15;
      float* op = Og + I.base0 + (long)(chunk*128 + 2*t + 0 - 1) * 768 + pp*4;
      *(float4*)op = z4;
    }
  } else if (gi == 2) {
    for (int i = tid; i < 192*16; i += 256) {
      const int row_i = i >> 4, pp = i & 15;
      const int t = row_i / 3, ddi = row_i - 3*t;
      const int dd = ddi + (ddi >= 2 ? 1 : 0);
      float* op = Og + I.base0 + (long)(chunk*256 + 4*t + dd - 2) * 768 + pp*4;
      *(float4*)op = z4;
    }
  }
}

// ---- pass 2: flash attention; PAIRED tiles per barrier (TK=128 effective) --
// Identical to the R11 structure except each stage/barrier period covers TWO
// 64-token tiles -> 8 barrier-drains instead of 16. 32 q-rows/wave, 4 waves.
__global__ __launch_bounds__(256, 2)
void dilated_attn2(const float* __restrict__ Qg,
                   const unsigned short* __restrict__ Ks,
                   const unsigned short* __restrict__ Vts,
                   const int* __restrict__ causal_flag,
                   float* __restrict__ Og)
{
  __shared__ __align__(16) unsigned short K_lds[2][2][64][64];  // 32 KB
  __shared__ __align__(16) unsigned short V_lds[2][2][64][64];  // 32 KB
  __shared__ __align__(16) unsigned short P_lds[4][16][64];     //  8 KB

  const int tid  = threadIdx.x;
  const int wave = tid >> 6;
  const int lane = tid & 63;
  const int l15  = lane & 15;
  const int l4   = lane >> 4;
  const int sw   = l15 & 7;            // row-XOR swizzle key (row&7)

  const int lid  = blockIdx.x;
  const int inst = lid % 56;           // 56%8==0 -> same inst => same XCD
  const int qt   = lid / 56;           // 8 q-blocks of 128 rows
  InstInfo I = decode_inst(inst);
  const int causal = *causal_flag;

  const float qscale = 0.125f * 1.44269504088896340736f;
  short8 b_q[2][2];
  int qrowf[2];
#pragma unroll
  for (int qf = 0; qf < 2; ++qf) {
    qrowf[qf] = qt*128 + wave*32 + qf*16 + l15;
    const float* qp = Qg + I.base0 + (long)qrowf[qf] * I.stride + l4 * 8;
#pragma unroll
    for (int ks = 0; ks < 2; ++ks) {
      float4 v0 = *(const float4*)(qp + ks*32);
      float4 v1 = *(const float4*)(qp + ks*32 + 4);
      v0.x *= qscale; v0.y *= qscale; v0.z *= qscale; v0.w *= qscale;
      v1.x *= qscale; v1.y *= qscale; v1.z *= qscale; v1.w *= qscale;
      b_q[qf][ks] = cvt8(v0, v1);
    }
  }

  short8 ones8;   // bf16 1.0 x8 (B operand for l row-sum MFMA)
  {
    union { unsigned u[4]; short8 s; } r;
    r.u[0] = r.u[1] = r.u[2] = r.u[3] = 0x3F803F80u;
    ones8 = r.s;
  }

  const unsigned short* KsI  = Ks  + (long)inst * (1024*64);
  const unsigned short* VtsI = Vts + (long)inst * (64*1024);
  const int vrow = lane >> 3;          // gll: 8 lanes per 128B row
  const int vcol = (lane & 7) * 8;

  // ---- loop-invariant addressing (verbatim R11) ----
  const long koffA = (long)(wave*8     + vrow)*64 + vcol;
  const long koffB = (long)((wave+4)*8 + vrow)*64 + vcol;
  const long voffA = (long)(wave*8     + vrow)*1024 + vcol;
  const long voffB = (long)((wave+4)*8 + vrow)*1024 + vcol;
  const int  colA  = ((l4 ^ sw) & 7) * 8;
  const int  colB  = (((4 + l4) ^ sw) & 7) * 8;
  const unsigned short* kb00 = &K_lds[0][0][l15][0];
  const unsigned short* kb01 = &K_lds[0][1][l15][0];
  const unsigned short* kb10 = &K_lds[1][0][l15][0];
  const unsigned short* kb11 = &K_lds[1][1][l15][0];
  const unsigned short* vb00 = &V_lds[0][0][l15][0];
  const unsigned short* vb01 = &V_lds[0][1][l15][0];
  const unsigned short* vb10 = &V_lds[1][0][l15][0];
  const unsigned short* vb11 = &V_lds[1][1][l15][0];
  unsigned short* pw = &P_lds[wave][l15][0];
  int pwo[4];
#pragma unroll
  for (int n = 0; n < 4; ++n)
    pwo[n] = (((2*n + (l4 >> 1)) ^ sw) & 7)*8 + (l4 & 1)*4;
  const int pro0 = colA;
  const int pro1 = colB;

  f32x4 Oacc[2][4];
  f32x4 accl[2];
#pragma unroll
  for (int qf = 0; qf < 2; ++qf) {
    accl[qf] = (f32x4){0.f,0.f,0.f,0.f};
#pragma unroll
    for (int n = 0; n < 4; ++n) Oacc[qf][n] = (f32x4){0.f,0.f,0.f,0.f};
  }

  // stage a PAIR of 64-token tiles (8 gll16/wave)
#define STAGE_PAIR(BUF, KP, VP) do {                                           \
    gll16((KP) + koffA,        &K_lds[BUF][0][wave*8][0]);                     \
    gll16((KP) + koffB,        &K_lds[BUF][0][(wave+4)*8][0]);                 \
    gll16((KP) + 4096 + koffA, &K_lds[BUF][1][wave*8][0]);                     \
    gll16((KP) + 4096 + koffB, &K_lds[BUF][1][(wave+4)*8][0]);                 \
    gll16((VP) + voffA,        &V_lds[BUF][0][wave*8][0]);                     \
    gll16((VP) + voffB,        &V_lds[BUF][0][(wave+4)*8][0]);                 \
    gll16((VP) + 64 + voffA,   &V_lds[BUF][1][wave*8][0]);                     \
    gll16((VP) + 64 + voffB,   &V_lds[BUF][1][(wave+4)*8][0]);                 \
  } while (0)

#define COMPUTE(BH, KT) do {                                                   \
    f32x4 S0[4], S1[4];                                                        \
    __builtin_amdgcn_s_setprio(1);                                             \
    _Pragma("unroll")                                                          \
    for (int n = 0; n < 4; ++n) {                                              \
      short8 kA = *(const short8*)(kb##BH + n*1024 + colA);                    \
      short8 kB = *(const short8*)(kb##BH + n*1024 + colB);                    \
      f32x4 a0 = (f32x4){0.f,0.f,0.f,0.f};                                     \
      a0 = __builtin_amdgcn_mfma_f32_16x16x32_bf16(kA, b_q[0][0], a0, 0,0,0);  \
      a0 = __builtin_amdgcn_mfma_f32_16x16x32_bf16(kB, b_q[0][1], a0, 0,0,0);  \
      S0[n] = a0;                                                              \
      f32x4 a1 = (f32x4){0.f,0.f,0.f,0.f};                                     \
      a1 = __builtin_amdgcn_mfma_f32_16x16x32_bf16(kA, b_q[1][0], a1, 0,0,0);  \
      a1 = __builtin_amdgcn_mfma_f32_16x16x32_bf16(kB, b_q[1][1], a1, 0,0,0);  \
      S1[n] = a1;                                                              \
    }                                                                          \
    __builtin_amdgcn_s_setprio(0);                                             \
    if (causal) {                                                              \
      _Pragma("unroll")                                                        \
      for (int n = 0; n < 4; ++n)                                              \
        _Pragma("unroll")                                                      \
        for (int j = 0; j < 4; ++j) {                                          \
          int ktok = (KT)*64 + n*16 + l4*4 + j;                                \
          if (ktok > qrowf[0]) S0[n][j] = -INFINITY;                           \
          if (ktok > qrowf[1]) S1[n][j] = -INFINITY;                           \
        }                                                                      \
    }                                                                          \
    short8 ap0a, ap0b, ap1a, ap1b;                                             \
    {                                                                          \
      _Pragma("unroll")                                                        \
      for (int n = 0; n < 4; ++n) {                                            \
        unsigned u0 = pk2(__builtin_amdgcn_exp2f(S0[n][0]),                    \
                          __builtin_amdgcn_exp2f(S0[n][1]));                   \
        unsigned u1 = pk2(__builtin_amdgcn_exp2f(S0[n][2]),                    \
                          __builtin_amdgcn_exp2f(S0[n][3]));                   \
        *(uint2*)(pw + pwo[n]) = make_uint2(u0, u1);                           \
      }                                                                        \
      ap0a = *(const short8*)(pw + pro0);                                      \
      ap0b = *(const short8*)(pw + pro1);                                      \
      accl[0] = __builtin_amdgcn_mfma_f32_16x16x32_bf16(ap0a, ones8, accl[0], 0,0,0); \
      accl[0] = __builtin_amdgcn_mfma_f32_16x16x32_bf16(ap0b, ones8, accl[0], 0,0,0); \
    }                                                                          \
    {                                                                          \
      _Pragma("unroll")                                                        \
      for (int n = 0; n < 4; ++n) {                                            \
        unsigned u0 = pk2(__builtin_amdgcn_exp2f(S1[n][0]),                    \
                          __builtin_amdgcn_exp2f(S1[n][1]));                   \
        unsigned u1 = pk2(__builtin_amdgcn_exp2f(S1[n][2]),                    \
                          __builtin_amdgcn_exp2f(S1[n][3]));                   \
        *(uint2*)(pw + pwo[n]) = make_uint2(u0, u1);                           \
      }                                                                        \
      ap1a = *(const short8*)(pw + pro0);                                      \
      ap1b = *(const short8*)(pw + pro1);                                      \
      accl[1] = __builtin_amdgcn_mfma_f32_16x16x32_bf16(ap1a, ones8, accl[1], 0,0,0); \
      accl[1] = __builtin_amdgcn_mfma_f32_16x16x32_bf16(ap1b, ones8, accl[1], 0,0,0); \
    }                                                                          \
    _Pragma("unroll")                                                          \
    for (int n = 0; n < 4; ++n) {                                              \
      short8 bv0 = *(const short8*)(vb##BH + n*1024 + colA);                   \
      short8 bv1 = *(const short8*)(vb##BH + n*1024 + colB);                   \
      __builtin_amdgcn_s_setprio(1);                                           \
      Oacc[0][n] = __builtin_amdgcn_mfma_f32_16x16x32_bf16(ap0a, bv0, Oacc[0][n], 0,0,0); \
      Oacc[0][n] = __builtin_amdgcn_mfma_f32_16x16x32_bf16(ap0b, bv1, Oacc[0][n], 0,0,0); \
      Oacc[1][n] = __builtin_amdgcn_mfma_f32_16x16x32_bf16(ap1a, bv0, Oacc[1][n], 0,0,0); \
      Oacc[1][n] = __builtin_amdgcn_mfma_f32_16x16x32_bf16(ap1b, bv1, Oacc[1][n], 0,0,0); \
      __builtin_amdgcn_s_setprio(0);                                           \
    }                                                                          \
  } while (0)

  // ---- prologue: pair 0 -> buffer 0 ----
  STAGE_PAIR(0, KsI, VtsI);
  __syncthreads();

  const unsigned short* kp1 = KsI + 8192;      // pair kt/2 + 1
  const unsigned short* kp2 = KsI + 16384;     // pair kt/2 + 2
  const unsigned short* vp1 = VtsI + 128;
  const unsigned short* vp2 = VtsI + 256;

  for (int p = 0; p < NTILE/4; ++p) {          // 4 iterations, 2 pairs each
    const int kt = 4*p;
    STAGE_PAIR(1, kp1, vp1);
    COMPUTE(00, kt);
    COMPUTE(01, kt + 1);
    __syncthreads();
    if (p < NTILE/4 - 1) STAGE_PAIR(0, kp2, vp2);
    COMPUTE(10, kt + 2);
    COMPUTE(11, kt + 3);
    __syncthreads();
    kp1 += 16384; kp2 += 16384; vp1 += 256; vp2 += 256;
  }

  // ---- epilogue: O / l, dilated scatter ----
  float* ob = Og + I.base0;
#pragma unroll
  for (int qf = 0; qf < 2; ++qf)
#pragma unroll
    for (int j = 0; j < 4; ++j) {
      const float inv = 1.f / accl[qf][j];
      const int qrow = qt*128 + wave*32 + qf*16 + l4*4 + j;
      float* op = ob + (long)qrow * I.stride;
#pragma unroll
      for (int n = 0; n < 4; ++n)
        op[n*16 + l15] = Oacc[qf][n][j] * inv;
    }
}

// ---------------- fallback (R4 kernel) if workspace too small ---------------
#define LDP 72
__global__ __launch_bounds__(512, 4)
void dilated_attn_fb(const float* __restrict__ Qg,
                     const float* __restrict__ Kg,
                     const float* __restrict__ Vg,
                     const int* __restrict__ causal_flag,
                     float* __restrict__ Og)
{
  __shared__ __align__(16) unsigned short K_lds[2][64][LDP];
  __shared__ __align__(16) unsigned short Vt_lds[2][64][LDP];
  __shared__ __align__(16) unsigned short P_lds[8][16][LDP];

  const int tid  = threadIdx.x;
  const int wave = tid >> 6;
  const int lane = tid & 63;
  const int l15  = lane & 15;
  const int l4   = lane >> 4;
  const int qt   = blockIdx.x;
  InstInfo I = decode_inst(blockIdx.y);
  const int causal = *causal_flag;

  const float qscale = 0.125f * 1.44269504088896340736f;
  short8 b_q[2];
  {
    const int qrow = qt * 128 + wave * 16 + l15;
    const float* qp = Qg + I.base0 + (long)qrow * I.stride + l4 * 8;
#pragma unroll
    for (int ks = 0; ks < 2; ++ks) {
      float4 v0 = *(const float4*)(qp + ks * 32);
      float4 v1 = *(const float4*)(qp + ks * 32 + 4);
      v0.x *= qscale; v0.y *= qscale; v0.z *= qscale; v0.w *= qscale;
      v1.x *= qscale; v1.y *= qscale; v1.z *= qscale; v1.w *= qscale;
      b_q[ks] = cvt8(v0, v1);
    }
  }
  float m_run = -INFINITY, l_run = 0.f;
  f32x4 Oacc[4];
#pragma unroll
  for (int n = 0; n < 4; ++n) Oacc[n] = (f32x4){0.f,0.f,0.f,0.f};
  const int tt  = tid >> 3;
  const int cb8 = tid & 7;
  const float* kbase = Kg + I.base0 + cb8 * 8;
  const float* vbase = Vg + I.base0 + cb8 * 8;
#define STAGE_FB(BUF, A0, A1, W0, W1) do {                                     \
    *(short8*)&K_lds[BUF][tt][cb8 * 8] = cvt8(A0, A1);                         \
    unsigned p01 = pk2(W0.x, W0.y), p23 = pk2(W0.z, W0.w);                     \
    unsigned p45 = pk2(W1.x, W1.y), p67 = pk2(W1.z, W1.w);                     \
    const int col = (((tt >> 3) ^ cb8) << 3) | (tt & 7);                       \
    Vt_lds[BUF][cb8*8+0][col] = (unsigned short)(p01 & 0xffff);                \
    Vt_lds[BUF][cb8*8+1][col] = (unsigned short)(p01 >> 16);                   \
    Vt_lds[BUF][cb8*8+2][col] = (unsigned short)(p23 & 0xffff);                \
    Vt_lds[BUF][cb8*8+3][col] = (unsigned short)(p23 >> 16);                   \
    Vt_lds[BUF][cb8*8+4][col] = (unsigned short)(p45 & 0xffff);                \
    Vt_lds[BUF][cb8*8+5][col] = (unsigned short)(p45 >> 16);                   \
    Vt_lds[BUF][cb8*8+6][col] = (unsigned short)(p67 & 0xffff);                \
    Vt_lds[BUF][cb8*8+7][col] = (unsigned short)(p67 >> 16);                   \
  } while (0)
  {
    const long ro = (long)tt * I.stride;
    float4 k0 = *(const float4*)(kbase + ro);
    float4 k1 = *(const float4*)(kbase + ro + 4);
    float4 w0 = *(const float4*)(vbase + ro);
    float4 w1 = *(const float4*)(vbase + ro + 4);
    STAGE_FB(0, k0, k1, w0, w1);
  }
  __syncthreads();
  const int qrow_me = qt * 128 + wave * 16 + l15;
  for (int kt = 0; kt < NTILE; ++kt) {
    const int bsel = kt & 1;
    float4 nk0, nk1, nw0, nw1;
    const bool have_next = (kt + 1 < NTILE);
    if (have_next) {
      const long ro = (long)((kt + 1) * 64 + tt) * I.stride;
      nk0 = *(const float4*)(kbase + ro);
      nk1 = *(const float4*)(kbase + ro + 4);
      nw0 = *(const float4*)(vbase + ro);
      nw1 = *(const float4*)(vbase + ro + 4);
    }
    f32x4 S[4];
#pragma unroll
    for (int n = 0; n < 4; ++n) {
      short8 ak0 = *(const short8*)&K_lds[bsel][n*16 + l15][l4*8];
      short8 ak1 = *(const short8*)&K_lds[bsel][n*16 + l15][32 + l4*8];
      f32x4 acc = (f32x4){0.f,0.f,0.f,0.f};
      acc = __builtin_amdgcn_mfma_f32_16x16x32_bf16(ak0, b_q[0], acc, 0,0,0);
      acc = __builtin_amdgcn_mfma_f32_16x16x32_bf16(ak1, b_q[1], acc, 0,0,0);
      S[n] = acc;
    }
    if (causal) {
#pragma unroll
      for (int n = 0; n < 4; ++n)
#pragma unroll
        for (int j = 0; j < 4; ++j) {
          int ktok = kt*64 + n*16 + l4*4 + j;
          if (ktok > qrow_me) S[n][j] = -INFINITY;
        }
    }
    float pmax = S[0][0];
#pragma unroll
    for (int n = 0; n < 4; ++n)
#pragma unroll
      for (int j = 0; j < 4; ++j) pmax = fmaxf(pmax, S[n][j]);
    pmax = fmaxf(pmax, __shfl_xor(pmax, 16));
    pmax = fmaxf(pmax, __shfl_xor(pmax, 32));
    if (!__all(pmax - m_run <= 8.f)) {
      float mn = fmaxf(m_run, pmax);
      float corr = exp2f(m_run - mn);
      m_run = mn; l_run *= corr;
      float cq[4];
#pragma unroll
      for (int j = 0; j < 4; ++j) cq[j] = __shfl(corr, l4*4 + j, 16);
#pragma unroll
      for (int n = 0; n < 4; ++n)
#pragma unroll
        for (int j = 0; j < 4; ++j) Oacc[n][j] *= cq[j];
    }
    float psum = 0.f; unsigned up[4][2];
#pragma unroll
    for (int n = 0; n < 4; ++n)
#pragma unroll
      for (int s = 0; s < 2; ++s) {
        float p0 = exp2f(S[n][2*s]   - m_run);
        float p1 = exp2f(S[n][2*s+1] - m_run);
        psum += p0 + p1; up[n][s] = pk2(p0, p1);
      }
    l_run += psum;
#pragma unroll
    for (int n = 0; n < 4; ++n)
      *(uint2*)&P_lds[wave][l15][n*16 + l4*4] = make_uint2(up[n][0], up[n][1]);
    {
      short8 ap0 = *(const short8*)&P_lds[wave][l15][l4*8];
      short8 ap1 = *(const short8*)&P_lds[wave][l15][32 + l4*8];
#pragma unroll
      for (int n = 0; n < 4; ++n) {
        const int dsw = (2*n + (l15 >> 3)) & 7;
        short8 bv0 = *(const short8*)&Vt_lds[bsel][n*16 + l15][((l4 ^ dsw) & 7)*8];
        short8 bv1 = *(const short8*)&Vt_lds[bsel][n*16 + l15][(((4 + l4) ^ dsw) & 7)*8];
        Oacc[n] = __builtin_amdgcn_mfma_f32_16x16x32_bf16(ap0, bv0, Oacc[n], 0,0,0);
        Oacc[n] = __builtin_amdgcn_mfma_f32_16x16x32_bf16(ap1, bv1, Oacc[n], 0,0,0);
      }
    }
    if (have_next) STAGE_FB(bsel ^ 1, nk0, nk1, nw0, nw1);
    __syncthreads();
  }
  l_run += __shfl_xor(l_run, 16);
  l_run += __shfl_xor(l_run, 32);
  float lq[4];
#pragma unroll
  for (int j = 0; j < 4; ++j) lq[j] = __shfl(l_run, l4*4 + j, 16);
  float* ob = Og + I.base0;
#pragma unroll
  for (int j = 0; j < 4; ++j) {
    const float inv = 1.f / lq[j];
    const int qrow = qt*128 + wave*16 + l4*4 + j;
    float* op = ob + (long)qrow * I.stride;
#pragma unroll
    for (int n = 0; n < 4; ++n)
      op[n*16 + l15] = Oacc[n][j] * inv;
  }
}

extern "C" void kernel_launch(void* const* d_in, const int* in_sizes, int n_in,
                              void* d_out, int out_size, void* d_ws, size_t ws_size,
                              hipStream_t stream) {
  const float* Q = (const float*)d_in[0];
  const float* K = (const float*)d_in[1];
  const float* V = (const float*)d_in[2];
  const int* causal = (const int*)d_in[3];
  float* out = (float*)d_out;

  const size_t per = 56ull * 1024 * 64;               // elems per packed tensor
  const size_t need_pack = 2 * per * sizeof(unsigned short);   // 14.68 MB

  if (ws_size >= need_pack) {
    unsigned short* Ks  = (unsigned short*)d_ws;
    unsigned short* Vts = Ks + per;
    // pack_kv also zeroes the dilation holes -> no output memset needed
    pack_kv<<<896, 256, 0, stream>>>(K, V, Ks, Vts, out);
    dilated_attn2<<<448, 256, 0, stream>>>(Q, Ks, Vts, causal, out);
  } else {
    (void)hipMemsetAsync(d_out, 0, (size_t)out_size * sizeof(float), stream);
    dilated_attn_fb<<<dim3(8, 56), 512, 0, stream>>>(Q, K, V, causal, out);
  }
}

// Round 16
// 39.969 us; speedup vs baseline: 1.9043x; 1.0141x over previous
//
#include <hip/hip_runtime.h>
#include <hip/hip_bf16.h>

typedef __attribute__((ext_vector_type(8))) short short8;
typedef __attribute__((ext_vector_type(4))) float f32x4;

#define NTILE 16

static __device__ __forceinline__ unsigned pk2(float x, float y) {
  // v_cvt_pk_bf16_f32 (RNE)
  __hip_bfloat162 h = __float22bfloat162_rn(make_float2(x, y));
  unsigned u; __builtin_memcpy(&u, &h, 4); return u;
}

static __device__ __forceinline__ short8 cvt8(float4 a, float4 b) {
  union { unsigned u[4]; short8 s; } r;
  r.u[0] = pk2(a.x, a.y); r.u[1] = pk2(a.z, a.w);
  r.u[2] = pk2(b.x, b.y); r.u[3] = pk2(b.z, b.w);
  return r.s;
}

static __device__ __forceinline__ void gll16(const void* g, void* l) {
  // global -> LDS DMA, 16B/lane; LDS dest = wave-uniform base + lane*16
  __builtin_amdgcn_global_load_lds(
      (__attribute__((address_space(1))) void*)const_cast<void*>(g),
      (__attribute__((address_space(3))) void*)(l), 16, 0, 0);
}

// ---- counted-vmcnt sync primitives (T4): loads stay in flight across barriers
#define WAIT8_BAR() do {                                                       \
    asm volatile("s_waitcnt vmcnt(8)" ::: "memory");                           \
    __builtin_amdgcn_sched_barrier(0);                                         \
    __builtin_amdgcn_s_barrier();                                              \
    __builtin_amdgcn_sched_barrier(0);                                         \
  } while (0)
#define WAIT0_BAR() do {                                                       \
    asm volatile("s_waitcnt vmcnt(0)" ::: "memory");                           \
    __builtin_amdgcn_sched_barrier(0);                                         \
    __builtin_amdgcn_s_barrier();                                              \
    __builtin_amdgcn_sched_barrier(0);                                         \
  } while (0)
#define BAR() do {                                                             \
    __builtin_amdgcn_sched_barrier(0);                                         \
    __builtin_amdgcn_s_barrier();                                              \
    __builtin_amdgcn_sched_barrier(0);                                         \
  } while (0)

struct InstInfo { long base0; int stride; };
static __device__ __forceinline__ InstInfo decode_inst(int inst) {
  const int gi    = (inst < 32) ? 0 : ((inst < 48) ? 1 : 2);
  const int local = inst - ((gi == 0) ? 0 : ((gi == 1) ? 32 : 48));
  const int segs  = 4 >> gi;
  const int g     = 1024 << gi;
  const int offs  = gi;                // i % r = 0,1,2 for the three groups
  const int h     = local & 3;
  const int rem   = local >> 2;
  const int seg   = rem & (segs - 1);
  const int b     = rem >> (2 - gi);
  const int hh    = gi * 4 + h;
  InstInfo r;
  r.base0  = ((long)(b * 4096 + seg * g + offs) * 12 + hh) * 64;
  r.stride = (1 << gi) * 768;
  return r;
}

// ---- pass 1: K/V gather + bf16 pack (XOR-16B-block swizzle baked) + holes --
__global__ __launch_bounds__(256)
void pack_kv(const float* __restrict__ Kg, const float* __restrict__ Vg,
             unsigned short* __restrict__ Ks, unsigned short* __restrict__ Vts,
             float* __restrict__ Og)
{
  __shared__ float vtmp[64][65];
  const int tid   = threadIdx.x;
  const int lid   = blockIdx.x;
  const int inst  = lid % 56;
  const int chunk = lid / 56;          // 64-token chunk (== pass-2 k-tile)
  const int gi    = (inst < 32) ? 0 : ((inst < 48) ? 1 : 2);
  InstInfo I = decode_inst(inst);

  {
    const int tok = tid >> 2, part = tid & 3;
    const long ro = I.base0 + (long)(chunk * 64 + tok) * I.stride + part * 16;
    const float4 k0 = *(const float4*)(Kg + ro);
    const float4 k1 = *(const float4*)(Kg + ro + 4);
    const float4 k2 = *(const float4*)(Kg + ro + 8);
    const float4 k3 = *(const float4*)(Kg + ro + 12);
    uint4 ka, kb;
    ka.x = pk2(k0.x,k0.y); ka.y = pk2(k0.z,k0.w); ka.z = pk2(k1.x,k1.y); ka.w = pk2(k1.z,k1.w);
    kb.x = pk2(k2.x,k2.y); kb.y = pk2(k2.z,k2.w); kb.z = pk2(k3.x,k3.y); kb.w = pk2(k3.z,k3.w);
    // K: row tok of 64 elems = 8 x 16B blocks; block c stored at c ^ (tok&7)
    unsigned short* kd = Ks + ((long)inst*1024 + chunk*64 + tok)*64;
    const int c0 = (2*part)     ^ (tok & 7);
    const int c1 = (2*part + 1) ^ (tok & 7);
    *(uint4*)(kd + c0*8) = ka;
    *(uint4*)(kd + c1*8) = kb;

    const float4 w0 = *(const float4*)(Vg + ro);
    const float4 w1 = *(const float4*)(Vg + ro + 4);
    const float4 w2 = *(const float4*)(Vg + ro + 8);
    const float4 w3 = *(const float4*)(Vg + ro + 12);
    float* c = &vtmp[part*16][0] + tok;
    c[0*65]=w0.x;  c[1*65]=w0.y;  c[2*65]=w0.z;  c[3*65]=w0.w;
    c[4*65]=w1.x;  c[5*65]=w1.y;  c[6*65]=w1.z;  c[7*65]=w1.w;
    c[8*65]=w2.x;  c[9*65]=w2.y;  c[10*65]=w2.z; c[11*65]=w2.w;
    c[12*65]=w3.x; c[13*65]=w3.y; c[14*65]=w3.z; c[15*65]=w3.w;
  }
  __syncthreads();
  {
    const int d = tid >> 2, kp = tid & 3;
    float v[16];
#pragma unroll
    for (int i = 0; i < 16; ++i) v[i] = vtmp[d][kp*16 + i];
    unsigned short* vd = Vts + ((long)inst*64 + d)*1024 + chunk*64;
#pragma unroll
    for (int s = 0; s < 2; ++s) {
      const int pos = (kp*2 + s) ^ (d & 7);      // 16B-block swizzle baked in
      uint4 w;
      w.x = pk2(v[8*s+0], v[8*s+1]); w.y = pk2(v[8*s+2], v[8*s+3]);
      w.z = pk2(v[8*s+4], v[8*s+5]); w.w = pk2(v[8*s+6], v[8*s+7]);
      *(uint4*)(vd + pos*8) = w;
    }
  }

  // ---- zero the dilation holes of this block's span ----
  const float4 z4 = make_float4(0.f, 0.f, 0.f, 0.f);
  if (gi == 1) {
    for (int i = tid; i < 64*16; i += 256) {
      const int t = i >> 4, pp = i & 15;
      float* op = Og + I.base0 + (long)(chunk*128 + 2*t + 0 - 1) * 768 + pp*4;
      *(float4*)op = z4;
    }
  } else if (gi == 2) {
    for (int i = tid; i < 192*16; i += 256) {
      const int row_i = i >> 4, pp = i & 15;
      const int t = row_i / 3, ddi = row_i - 3*t;
      const int dd = ddi + (ddi >= 2 ? 1 : 0);
      float* op = Og + I.base0 + (long)(chunk*256 + 4*t + dd - 2) * 768 + pp*4;
      *(float4*)op = z4;
    }
  }
}

// ---- pass 2: flash attention; paired tiles + COUNTED vmcnt (T4) ------------
// Same as R15 except all __syncthreads replaced by raw barriers; staging loads
// stay in flight across barriers (vmcnt(8) waits only for the PREVIOUS pair).
__global__ __launch_bounds__(256, 2)
void dilated_attn2(const float* __restrict__ Qg,
                   const unsigned short* __restrict__ Ks,
                   const unsigned short* __restrict__ Vts,
                   const int* __restrict__ causal_flag,
                   float* __restrict__ Og)
{
  __shared__ __align__(16) unsigned short K_lds[2][2][64][64];  // 32 KB
  __shared__ __align__(16) unsigned short V_lds[2][2][64][64];  // 32 KB
  __shared__ __align__(16) unsigned short P_lds[4][16][64];     //  8 KB

  const int tid  = threadIdx.x;
  const int wave = tid >> 6;
  const int lane = tid & 63;
  const int l15  = lane & 15;
  const int l4   = lane >> 4;
  const int sw   = l15 & 7;            // row-XOR swizzle key (row&7)

  const int lid  = blockIdx.x;
  const int inst = lid % 56;           // 56%8==0 -> same inst => same XCD
  const int qt   = lid / 56;           // 8 q-blocks of 128 rows
  InstInfo I = decode_inst(inst);
  const int causal = *causal_flag;

  const float qscale = 0.125f * 1.44269504088896340736f;
  short8 b_q[2][2];
  int qrowf[2];
#pragma unroll
  for (int qf = 0; qf < 2; ++qf) {
    qrowf[qf] = qt*128 + wave*32 + qf*16 + l15;
    const float* qp = Qg + I.base0 + (long)qrowf[qf] * I.stride + l4 * 8;
#pragma unroll
    for (int ks = 0; ks < 2; ++ks) {
      float4 v0 = *(const float4*)(qp + ks*32);
      float4 v1 = *(const float4*)(qp + ks*32 + 4);
      v0.x *= qscale; v0.y *= qscale; v0.z *= qscale; v0.w *= qscale;
      v1.x *= qscale; v1.y *= qscale; v1.z *= qscale; v1.w *= qscale;
      b_q[qf][ks] = cvt8(v0, v1);
    }
  }

  short8 ones8;   // bf16 1.0 x8 (B operand for l row-sum MFMA)
  {
    union { unsigned u[4]; short8 s; } r;
    r.u[0] = r.u[1] = r.u[2] = r.u[3] = 0x3F803F80u;
    ones8 = r.s;
  }

  const unsigned short* KsI  = Ks  + (long)inst * (1024*64);
  const unsigned short* VtsI = Vts + (long)inst * (64*1024);
  const int vrow = lane >> 3;          // gll: 8 lanes per 128B row
  const int vcol = (lane & 7) * 8;

  // ---- loop-invariant addressing ----
  const long koffA = (long)(wave*8     + vrow)*64 + vcol;
  const long koffB = (long)((wave+4)*8 + vrow)*64 + vcol;
  const long voffA = (long)(wave*8     + vrow)*1024 + vcol;
  const long voffB = (long)((wave+4)*8 + vrow)*1024 + vcol;
  const int  colA  = ((l4 ^ sw) & 7) * 8;
  const int  colB  = (((4 + l4) ^ sw) & 7) * 8;
  const unsigned short* kb00 = &K_lds[0][0][l15][0];
  const unsigned short* kb01 = &K_lds[0][1][l15][0];
  const unsigned short* kb10 = &K_lds[1][0][l15][0];
  const unsigned short* kb11 = &K_lds[1][1][l15][0];
  const unsigned short* vb00 = &V_lds[0][0][l15][0];
  const unsigned short* vb01 = &V_lds[0][1][l15][0];
  const unsigned short* vb10 = &V_lds[1][0][l15][0];
  const unsigned short* vb11 = &V_lds[1][1][l15][0];
  unsigned short* pw = &P_lds[wave][l15][0];
  int pwo[4];
#pragma unroll
  for (int n = 0; n < 4; ++n)
    pwo[n] = (((2*n + (l4 >> 1)) ^ sw) & 7)*8 + (l4 & 1)*4;
  const int pro0 = colA;
  const int pro1 = colB;

  f32x4 Oacc[2][4];
  f32x4 accl[2];
#pragma unroll
  for (int qf = 0; qf < 2; ++qf) {
    accl[qf] = (f32x4){0.f,0.f,0.f,0.f};
#pragma unroll
    for (int n = 0; n < 4; ++n) Oacc[qf][n] = (f32x4){0.f,0.f,0.f,0.f};
  }

  // stage a PAIR of 64-token tiles (8 gll16/wave)
#define STAGE_PAIR(BUF, KP, VP) do {                                           \
    gll16((KP) + koffA,        &K_lds[BUF][0][wave*8][0]);                     \
    gll16((KP) + koffB,        &K_lds[BUF][0][(wave+4)*8][0]);                 \
    gll16((KP) + 4096 + koffA, &K_lds[BUF][1][wave*8][0]);                     \
    gll16((KP) + 4096 + koffB, &K_lds[BUF][1][(wave+4)*8][0]);                 \
    gll16((VP) + voffA,        &V_lds[BUF][0][wave*8][0]);                     \
    gll16((VP) + voffB,        &V_lds[BUF][0][(wave+4)*8][0]);                 \
    gll16((VP) + 64 + voffA,   &V_lds[BUF][1][wave*8][0]);                     \
    gll16((VP) + 64 + voffB,   &V_lds[BUF][1][(wave+4)*8][0]);                 \
  } while (0)

#define COMPUTE(BH, KT) do {                                                   \
    f32x4 S0[4], S1[4];                                                        \
    __builtin_amdgcn_s_setprio(1);                                             \
    _Pragma("unroll")                                                          \
    for (int n = 0; n < 4; ++n) {                                              \
      short8 kA = *(const short8*)(kb##BH + n*1024 + colA);                    \
      short8 kB = *(const short8*)(kb##BH + n*1024 + colB);                    \
      f32x4 a0 = (f32x4){0.f,0.f,0.f,0.f};                                     \
      a0 = __builtin_amdgcn_mfma_f32_16x16x32_bf16(kA, b_q[0][0], a0, 0,0,0);  \
      a0 = __builtin_amdgcn_mfma_f32_16x16x32_bf16(kB, b_q[0][1], a0, 0,0,0);  \
      S0[n] = a0;                                                              \
      f32x4 a1 = (f32x4){0.f,0.f,0.f,0.f};                                     \
      a1 = __builtin_amdgcn_mfma_f32_16x16x32_bf16(kA, b_q[1][0], a1, 0,0,0);  \
      a1 = __builtin_amdgcn_mfma_f32_16x16x32_bf16(kB, b_q[1][1], a1, 0,0,0);  \
      S1[n] = a1;                                                              \
    }                                                                          \
    __builtin_amdgcn_s_setprio(0);                                             \
    if (causal) {                                                              \
      _Pragma("unroll")                                                        \
      for (int n = 0; n < 4; ++n)                                              \
        _Pragma("unroll")                                                      \
        for (int j = 0; j < 4; ++j) {                                          \
          int ktok = (KT)*64 + n*16 + l4*4 + j;                                \
          if (ktok > qrowf[0]) S0[n][j] = -INFINITY;                           \
          if (ktok > qrowf[1]) S1[n][j] = -INFINITY;                           \
        }                                                                      \
    }                                                                          \
    short8 ap0a, ap0b, ap1a, ap1b;                                             \
    {                                                                          \
      _Pragma("unroll")                                                        \
      for (int n = 0; n < 4; ++n) {                                            \
        unsigned u0 = pk2(__builtin_amdgcn_exp2f(S0[n][0]),                    \
                          __builtin_amdgcn_exp2f(S0[n][1]));                   \
        unsigned u1 = pk2(__builtin_amdgcn_exp2f(S0[n][2]),                    \
                          __builtin_amdgcn_exp2f(S0[n][3]));                   \
        *(uint2*)(pw + pwo[n]) = make_uint2(u0, u1);                           \
      }                                                                        \
      ap0a = *(const short8*)(pw + pro0);                                      \
      ap0b = *(const short8*)(pw + pro1);                                      \
      accl[0] = __builtin_amdgcn_mfma_f32_16x16x32_bf16(ap0a, ones8, accl[0], 0,0,0); \
      accl[0] = __builtin_amdgcn_mfma_f32_16x16x32_bf16(ap0b, ones8, accl[0], 0,0,0); \
    }                                                                          \
    {                                                                          \
      _Pragma("unroll")                                                        \
      for (int n = 0; n < 4; ++n) {                                            \
        unsigned u0 = pk2(__builtin_amdgcn_exp2f(S1[n][0]),                    \
                          __builtin_amdgcn_exp2f(S1[n][1]));                   \
        unsigned u1 = pk2(__builtin_amdgcn_exp2f(S1[n][2]),                    \
                          __builtin_amdgcn_exp2f(S1[n][3]));                   \
        *(uint2*)(pw + pwo[n]) = make_uint2(u0, u1);                           \
      }                                                                        \
      ap1a = *(const short8*)(pw + pro0);                                      \
      ap1b = *(const short8*)(pw + pro1);                                      \
      accl[1] = __builtin_amdgcn_mfma_f32_16x16x32_bf16(ap1a, ones8, accl[1], 0,0,0); \
      accl[1] = __builtin_amdgcn_mfma_f32_16x16x32_bf16(ap1b, ones8, accl[1], 0,0,0); \
    }                                                                          \
    _Pragma("unroll")                                                          \
    for (int n = 0; n < 4; ++n) {                                              \
      short8 bv0 = *(const short8*)(vb##BH + n*1024 + colA);                   \
      short8 bv1 = *(const short8*)(vb##BH + n*1024 + colB);                   \
      __builtin_amdgcn_s_setprio(1);                                           \
      Oacc[0][n] = __builtin_amdgcn_mfma_f32_16x16x32_bf16(ap0a, bv0, Oacc[0][n], 0,0,0); \
      Oacc[0][n] = __builtin_amdgcn_mfma_f32_16x16x32_bf16(ap0b, bv1, Oacc[0][n], 0,0,0); \
      Oacc[1][n] = __builtin_amdgcn_mfma_f32_16x16x32_bf16(ap1a, bv0, Oacc[1][n], 0,0,0); \
      Oacc[1][n] = __builtin_amdgcn_mfma_f32_16x16x32_bf16(ap1b, bv1, Oacc[1][n], 0,0,0); \
      __builtin_amdgcn_s_setprio(0);                                           \
    }                                                                          \
  } while (0)

  // ---- prologue: pair 0 -> buffer 0 (8 loads in flight) ----
  STAGE_PAIR(0, KsI, VtsI);

  const unsigned short* kp = KsI + 8192;   // next pair base (pair 1)
  const unsigned short* vp = VtsI + 128;

  // iters 0..2: both phases use counted vmcnt(8); loads stay in flight
  for (int p = 0; p < 3; ++p) {
    const int kt = 4*p;
    STAGE_PAIR(1, kp, vp);                 // pair 2p+1 (+8 in flight)
    WAIT8_BAR();                           // pair 2p landed; barrier (no drain)
    COMPUTE(00, kt);
    COMPUTE(01, kt + 1);
    BAR();                                 // buf0 free
    STAGE_PAIR(0, kp + 8192, vp + 128);    // pair 2p+2 (+8)
    WAIT8_BAR();                           // pair 2p+1 landed
    COMPUTE(10, kt + 2);
    COMPUTE(11, kt + 3);
    BAR();                                 // buf1 free
    kp += 16384; vp += 256;
  }
  // peel p=3: pairs 6 (buf0, already in flight) and 7 (buf1)
  STAGE_PAIR(1, kp, vp);                   // pair 7
  WAIT8_BAR();                             // pair 6 landed
  COMPUTE(00, 12);
  COMPUTE(01, 13);
  WAIT0_BAR();                             // final drain: pair 7 landed
  COMPUTE(10, 14);
  COMPUTE(11, 15);

  // ---- epilogue: O / l, dilated scatter ----
  float* ob = Og + I.base0;
#pragma unroll
  for (int qf = 0; qf < 2; ++qf)
#pragma unroll
    for (int j = 0; j < 4; ++j) {
      const float inv = 1.f / accl[qf][j];
      const int qrow = qt*128 + wave*32 + qf*16 + l4*4 + j;
      float* op = ob + (long)qrow * I.stride;
#pragma unroll
      for (int n = 0; n < 4; ++n)
        op[n*16 + l15] = Oacc[qf][n][j] * inv;
    }
}

// ---------------- fallback (R4 kernel) if workspace too small ---------------
#define LDP 72
__global__ __launch_bounds__(512, 4)
void dilated_attn_fb(const float* __restrict__ Qg,
                     const float* __restrict__ Kg,
                     const float* __restrict__ Vg,
                     const int* __restrict__ causal_flag,
                     float* __restrict__ Og)
{
  __shared__ __align__(16) unsigned short K_lds[2][64][LDP];
  __shared__ __align__(16) unsigned short Vt_lds[2][64][LDP];
  __shared__ __align__(16) unsigned short P_lds[8][16][LDP];

  const int tid  = threadIdx.x;
  const int wave = tid >> 6;
  const int lane = tid & 63;
  const int l15  = lane & 15;
  const int l4   = lane >> 4;
  const int qt   = blockIdx.x;
  InstInfo I = decode_inst(blockIdx.y);
  const int causal = *causal_flag;

  const float qscale = 0.125f * 1.44269504088896340736f;
  short8 b_q[2];
  {
    const int qrow = qt * 128 + wave * 16 + l15;
    const float* qp = Qg + I.base0 + (long)qrow * I.stride + l4 * 8;
#pragma unroll
    for (int ks = 0; ks < 2; ++ks) {
      float4 v0 = *(const float4*)(qp + ks * 32);
      float4 v1 = *(const float4*)(qp + ks * 32 + 4);
      v0.x *= qscale; v0.y *= qscale; v0.z *= qscale; v0.w *= qscale;
      v1.x *= qscale; v1.y *= qscale; v1.z *= qscale; v1.w *= qscale;
      b_q[ks] = cvt8(v0, v1);
    }
  }
  float m_run = -INFINITY, l_run = 0.f;
  f32x4 Oacc[4];
#pragma unroll
  for (int n = 0; n < 4; ++n) Oacc[n] = (f32x4){0.f,0.f,0.f,0.f};
  const int tt  = tid >> 3;
  const int cb8 = tid & 7;
  const float* kbase = Kg + I.base0 + cb8 * 8;
  const float* vbase = Vg + I.base0 + cb8 * 8;
#define STAGE_FB(BUF, A0, A1, W0, W1) do {                                     \
    *(short8*)&K_lds[BUF][tt][cb8 * 8] = cvt8(A0, A1);                         \
    unsigned p01 = pk2(W0.x, W0.y), p23 = pk2(W0.z, W0.w);                     \
    unsigned p45 = pk2(W1.x, W1.y), p67 = pk2(W1.z, W1.w);                     \
    const int col = (((tt >> 3) ^ cb8) << 3) | (tt & 7);                       \
    Vt_lds[BUF][cb8*8+0][col] = (unsigned short)(p01 & 0xffff);                \
    Vt_lds[BUF][cb8*8+1][col] = (unsigned short)(p01 >> 16);                   \
    Vt_lds[BUF][cb8*8+2][col] = (unsigned short)(p23 & 0xffff);                \
    Vt_lds[BUF][cb8*8+3][col] = (unsigned short)(p23 >> 16);                   \
    Vt_lds[BUF][cb8*8+4][col] = (unsigned short)(p45 & 0xffff);                \
    Vt_lds[BUF][cb8*8+5][col] = (unsigned short)(p45 >> 16);                   \
    Vt_lds[BUF][cb8*8+6][col] = (unsigned short)(p67 & 0xffff);                \
    Vt_lds[BUF][cb8*8+7][col] = (unsigned short)(p67 >> 16);                   \
  } while (0)
  {
    const long ro = (long)tt * I.stride;
    float4 k0 = *(const float4*)(kbase + ro);
    float4 k1 = *(const float4*)(kbase + ro + 4);
    float4 w0 = *(const float4*)(vbase + ro);
    float4 w1 = *(const float4*)(vbase + ro + 4);
    STAGE_FB(0, k0, k1, w0, w1);
  }
  __syncthreads();
  const int qrow_me = qt * 128 + wave * 16 + l15;
  for (int kt = 0; kt < NTILE; ++kt) {
    const int bsel = kt & 1;
    float4 nk0, nk1, nw0, nw1;
    const bool have_next = (kt + 1 < NTILE);
    if (have_next) {
      const long ro = (long)((kt + 1) * 64 + tt) * I.stride;
      nk0 = *(const float4*)(kbase + ro);
      nk1 = *(const float4*)(kbase + ro + 4);
      nw0 = *(const float4*)(vbase + ro);
      nw1 = *(const float4*)(vbase + ro + 4);
    }
    f32x4 S[4];
#pragma unroll
    for (int n = 0; n < 4; ++n) {
      short8 ak0 = *(const short8*)&K_lds[bsel][n*16 + l15][l4*8];
      short8 ak1 = *(const short8*)&K_lds[bsel][n*16 + l15][32 + l4*8];
      f32x4 acc = (f32x4){0.f,0.f,0.f,0.f};
      acc = __builtin_amdgcn_mfma_f32_16x16x32_bf16(ak0, b_q[0], acc, 0,0,0);
      acc = __builtin_amdgcn_mfma_f32_16x16x32_bf16(ak1, b_q[1], acc, 0,0,0);
      S[n] = acc;
    }
    if (causal) {
#pragma unroll
      for (int n = 0; n < 4; ++n)
#pragma unroll
        for (int j = 0; j < 4; ++j) {
          int ktok = kt*64 + n*16 + l4*4 + j;
          if (ktok > qrow_me) S[n][j] = -INFINITY;
        }
    }
    float pmax = S[0][0];
#pragma unroll
    for (int n = 0; n < 4; ++n)
#pragma unroll
      for (int j = 0; j < 4; ++j) pmax = fmaxf(pmax, S[n][j]);
    pmax = fmaxf(pmax, __shfl_xor(pmax, 16));
    pmax = fmaxf(pmax, __shfl_xor(pmax, 32));
    if (!__all(pmax - m_run <= 8.f)) {
      float mn = fmaxf(m_run, pmax);
      float corr = exp2f(m_run - mn);
      m_run = mn; l_run *= corr;
      float cq[4];
#pragma unroll
      for (int j = 0; j < 4; ++j) cq[j] = __shfl(corr, l4*4 + j, 16);
#pragma unroll
      for (int n = 0; n < 4; ++n)
#pragma unroll
        for (int j = 0; j < 4; ++j) Oacc[n][j] *= cq[j];
    }
    float psum = 0.f; unsigned up[4][2];
#pragma unroll
    for (int n = 0; n < 4; ++n)
#pragma unroll
      for (int s = 0; s < 2; ++s) {
        float p0 = exp2f(S[n][2*s]   - m_run);
        float p1 = exp2f(S[n][2*s+1] - m_run);
        psum += p0 + p1; up[n][s] = pk2(p0, p1);
      }
    l_run += psum;
#pragma unroll
    for (int n = 0; n < 4; ++n)
      *(uint2*)&P_lds[wave][l15][n*16 + l4*4] = make_uint2(up[n][0], up[n][1]);
    {
      short8 ap0 = *(const short8*)&P_lds[wave][l15][l4*8];
      short8 ap1 = *(const short8*)&P_lds[wave][l15][32 + l4*8];
#pragma unroll
      for (int n = 0; n < 4; ++n) {
        const int dsw = (2*n + (l15 >> 3)) & 7;
        short8 bv0 = *(const short8*)&Vt_lds[bsel][n*16 + l15][((l4 ^ dsw) & 7)*8];
        short8 bv1 = *(const short8*)&Vt_lds[bsel][n*16 + l15][(((4 + l4) ^ dsw) & 7)*8];
        Oacc[n] = __builtin_amdgcn_mfma_f32_16x16x32_bf16(ap0, bv0, Oacc[n], 0,0,0);
        Oacc[n] = __builtin_amdgcn_mfma_f32_16x16x32_bf16(ap1, bv1, Oacc[n], 0,0,0);
      }
    }
    if (have_next) STAGE_FB(bsel ^ 1, nk0, nk1, nw0, nw1);
    __syncthreads();
  }
  l_run += __shfl_xor(l_run, 16);
  l_run += __shfl_xor(l_run, 32);
  float lq[4];
#pragma unroll
  for (int j = 0; j < 4; ++j) lq[j] = __shfl(l_run, l4*4 + j, 16);
  float* ob = Og + I.base0;
#pragma unroll
  for (int j = 0; j < 4; ++j) {
    const float inv = 1.f / lq[j];
    const int qrow = qt*128 + wave*16 + l4*4 + j;
    float* op = ob + (long)qrow * I.stride;
#pragma unroll
    for (int n = 0; n < 4; ++n)
      op[n*16 + l15] = Oacc[n][j] * inv;
  }
}

extern "C" void kernel_launch(void* const* d_in, const int* in_sizes, int n_in,
                              void* d_out, int out_size, void* d_ws, size_t ws_size,
                              hipStream_t stream) {
  const float* Q = (const float*)d_in[0];
  const float* K = (const float*)d_in[1];
  const float* V = (const float*)d_in[2];
  const int* causal = (const int*)d_in[3];
  float* out = (float*)d_out;

  const size_t per = 56ull * 1024 * 64;               // elems per packed tensor
  const size_t need_pack = 2 * per * sizeof(unsigned short);   // 14.68 MB

  if (ws_size >= need_pack) {
    unsigned short* Ks  = (unsigned short*)d_ws;
    unsigned short* Vts = Ks + per;
    // pack_kv also zeroes the dilation holes -> no output memset needed
    pack_kv<<<896, 256, 0, stream>>>(K, V, Ks, Vts, out);
    dilated_attn2<<<448, 256, 0, stream>>>(Q, Ks, Vts, causal, out);
  } else {
    (void)hipMemsetAsync(d_out, 0, (size_t)out_size * sizeof(float), stream);
    dilated_attn_fb<<<dim3(8, 56), 512, 0, stream>>>(Q, K, V, causal, out);
  }
}